// Round 1
// baseline (895.364 us; speedup 1.0000x reference)
//
#include <hip/hip_runtime.h>
#include <math.h>

// Problem constants (fixed by the reference)
constexpr int NN  = 4096;   // instances
constexpr int PP  = 2048;   // phrases
constexpr int EE  = 65536;  // edges
constexpr int DD  = 1024;   // feature dim
constexpr int OUTF = 128;   // gate MLP out dim
constexpr int G4  = 512;    // 4 gates * 128

__device__ __forceinline__ float sigmoid_relu(float z) {
    z = fmaxf(z, 0.0f);                 // sigmoid(relu(z)); z<=0 -> 0.5
    return 1.0f / (1.0f + __expf(-z));
}

// ---------------------------------------------------------------------------
// Pack the 4 gate weight matrices into per-side fused [1024][512] matrices.
// inst side: p_s tgt (rows D..2D), p_o tgt (D..2D), o_p src (0..D), s_p src (0..D)
// phra side: p_s src, p_o src, o_p tgt, s_p tgt.  Biases concat -> biascat[512].
__global__ void pack_kernel(const float* __restrict__ psW, const float* __restrict__ poW,
                            const float* __restrict__ opW, const float* __restrict__ spW,
                            const float* __restrict__ psB, const float* __restrict__ poB,
                            const float* __restrict__ opB, const float* __restrict__ spB,
                            float* __restrict__ Wi, float* __restrict__ Wp,
                            float* __restrict__ biascat) {
    int idx = blockIdx.x * blockDim.x + threadIdx.x;
    if (idx >= DD * OUTF) return;
    int k = idx >> 7, j = idx & 127;
    Wi[k * G4 +   0 + j] = psW[(DD + k) * OUTF + j];
    Wi[k * G4 + 128 + j] = poW[(DD + k) * OUTF + j];
    Wi[k * G4 + 256 + j] = opW[k * OUTF + j];
    Wi[k * G4 + 384 + j] = spW[k * OUTF + j];
    Wp[k * G4 +   0 + j] = psW[k * OUTF + j];
    Wp[k * G4 + 128 + j] = poW[k * OUTF + j];
    Wp[k * G4 + 256 + j] = opW[(DD + k) * OUTF + j];
    Wp[k * G4 + 384 + j] = spW[(DD + k) * OUTF + j];
    if (idx < G4) {
        int g = idx >> 7, jj = idx & 127;
        float v = (g == 0) ? psB[jj] : (g == 1) ? poB[jj] : (g == 2) ? opB[jj] : spB[jj];
        biascat[idx] = v;
    }
}

// ---------------------------------------------------------------------------
// Table GEMM: C[M][512] = A[M][1024] @ B[1024][512] (+ biascat).
// 64x64 tile, 256 threads, 4x4 microtile.
__global__ __launch_bounds__(256) void table_gemm_kernel(
        const float* __restrict__ A, const float* __restrict__ B,
        const float* __restrict__ biascat, float* __restrict__ C) {
    __shared__ float As[16][64];
    __shared__ float Bs[16][64];
    int bm = blockIdx.x * 64, bn = blockIdx.y * 64;
    int t = threadIdx.x;
    int tx = t & 15, ty = t >> 4;
    float acc[4][4] = {};
    int arow = t >> 2, ac4 = t & 3;
    int brow = t >> 4, bc4 = t & 15;
    for (int k0 = 0; k0 < DD; k0 += 16) {
        float4 av = *(const float4*)&A[(size_t)(bm + arow) * DD + k0 + ac4 * 4];
        As[ac4 * 4 + 0][arow] = av.x; As[ac4 * 4 + 1][arow] = av.y;
        As[ac4 * 4 + 2][arow] = av.z; As[ac4 * 4 + 3][arow] = av.w;
        *(float4*)&Bs[brow][bc4 * 4] =
            *(const float4*)&B[(size_t)(k0 + brow) * G4 + bn + bc4 * 4];
        __syncthreads();
        #pragma unroll
        for (int k = 0; k < 16; k++) {
            float a[4], b[4];
            *(float4*)a = *(const float4*)&As[k][ty * 4];
            *(float4*)b = *(const float4*)&Bs[k][tx * 4];
            #pragma unroll
            for (int i = 0; i < 4; i++)
                #pragma unroll
                for (int j = 0; j < 4; j++)
                    acc[i][j] = fmaf(a[i], b[j], acc[i][j]);
        }
        __syncthreads();
    }
    float4 bv = make_float4(0.f, 0.f, 0.f, 0.f);
    if (biascat) bv = *(const float4*)&biascat[bn + tx * 4];
    #pragma unroll
    for (int i = 0; i < 4; i++) {
        int row = bm + ty * 4 + i;
        float4 o;
        o.x = acc[i][0] + bv.x; o.y = acc[i][1] + bv.y;
        o.z = acc[i][2] + bv.z; o.w = acc[i][3] + bv.w;
        *(float4*)&C[(size_t)row * G4 + bn + tx * 4] = o;
    }
}

// ---------------------------------------------------------------------------
// Per-edge gates: one wave per edge; 4 gates; wave shuffle reduction over 128 cols.
__global__ __launch_bounds__(256) void gate_kernel(
        const int* __restrict__ s_idx, const int* __restrict__ o_idx,
        const int* __restrict__ c_idx,
        const float* __restrict__ Ti, const float* __restrict__ Tp,
        float* __restrict__ gates) {
    int gid = blockIdx.x * blockDim.x + threadIdx.x;
    int e = gid >> 6;
    int lane = gid & 63;
    if (e >= EE) return;
    int s = s_idx[e], o = o_idx[e], c = c_idx[e];
    const float* tis = Ti + (size_t)s * G4;
    const float* tio = Ti + (size_t)o * G4;
    const float* tpc = Tp + (size_t)c * G4;
    float s0 = 0.f, s1 = 0.f, s2 = 0.f, s3 = 0.f;
    #pragma unroll
    for (int h = 0; h < 2; h++) {
        int j = lane + h * 64;
        s0 += sigmoid_relu(tpc[j]       + tis[j]);        // p_s
        s1 += sigmoid_relu(tpc[128 + j] + tio[128 + j]);  // p_o
        s2 += sigmoid_relu(tpc[256 + j] + tio[256 + j]);  // o_p
        s3 += sigmoid_relu(tpc[384 + j] + tis[384 + j]);  // s_p
    }
    #pragma unroll
    for (int off = 32; off; off >>= 1) {
        s0 += __shfl_xor(s0, off);
        s1 += __shfl_xor(s1, off);
        s2 += __shfl_xor(s2, off);
        s3 += __shfl_xor(s3, off);
    }
    if (lane == 0) {
        const float inv = 1.0f / 128.0f;
        gates[e]          = s0 * inv;
        gates[EE + e]     = s1 * inv;
        gates[2 * EE + e] = s2 * inv;
        gates[3 * EE + e] = s3 * inv;
    }
}

// ---------------------------------------------------------------------------
// Counting sort machinery
__global__ void hist_kernel(const int* __restrict__ s_idx, const int* __restrict__ o_idx,
                            const int* __restrict__ c_idx,
                            int* cntS, int* cntO, int* cntC) {
    int e = blockIdx.x * blockDim.x + threadIdx.x;
    if (e >= EE) return;
    atomicAdd(&cntS[s_idx[e]], 1);
    atomicAdd(&cntO[o_idx[e]], 1);
    atomicAdd(&cntC[c_idx[e]], 1);
}

__global__ __launch_bounds__(1024) void scan_kernel(const int* __restrict__ cnt,
                                                    int* __restrict__ start, int n) {
    __shared__ int sh[1024];
    int t = threadIdx.x;
    int per = n >> 10;  // n is 4096 or 2048, divisible by 1024
    int base = t * per;
    int s = 0;
    for (int i = 0; i < per; i++) s += cnt[base + i];
    sh[t] = s;
    __syncthreads();
    for (int off = 1; off < 1024; off <<= 1) {
        int v = (t >= off) ? sh[t - off] : 0;
        __syncthreads();
        sh[t] += v;
        __syncthreads();
    }
    int ex = (t == 0) ? 0 : sh[t - 1];
    for (int i = 0; i < per; i++) { start[base + i] = ex; ex += cnt[base + i]; }
    if (t == 1023) start[n] = ex;
}

__global__ void scatter_kernel(const int* __restrict__ s_idx, const int* __restrict__ o_idx,
                               const int* __restrict__ c_idx,
                               const int* __restrict__ startS, const int* __restrict__ startO,
                               const int* __restrict__ startC,
                               int* curS, int* curO, int* curC,
                               int* listS, int* listO, int* listC) {
    int e = blockIdx.x * blockDim.x + threadIdx.x;
    if (e >= EE) return;
    int s = s_idx[e];
    listS[startS[s] + atomicAdd(&curS[s], 1)] = e;
    int o = o_idx[e];
    listO[startO[o] + atomicAdd(&curO[o], 1)] = e;
    int c = c_idx[e];
    listC[startC[c] + atomicAdd(&curC[c], 1)] = e;
}

// ---------------------------------------------------------------------------
// Segment means.  inst side: msg_i = 0.5*(sum_s gate_ps*phra[c]/cntS + sum_o gate_po*phra[c]/cntO)
__global__ __launch_bounds__(256) void seg_inst_kernel(
        const float4* __restrict__ phra4, const int* __restrict__ c_idx,
        const float* __restrict__ gates,
        const int* __restrict__ listS, const int* __restrict__ startS,
        const int* __restrict__ listO, const int* __restrict__ startO,
        float4* __restrict__ msg4) {
    int node = blockIdx.x, t = threadIdx.x;
    const float* gate_ps = gates;
    const float* gate_po = gates + EE;
    float4 accS = make_float4(0.f, 0.f, 0.f, 0.f);
    float4 accO = make_float4(0.f, 0.f, 0.f, 0.f);
    int sb = startS[node], se = startS[node + 1];
    for (int i = sb; i < se; i++) {
        int e = listS[i];
        float g = gate_ps[e];
        int c = c_idx[e];
        float4 v = phra4[(size_t)c * 256 + t];
        accS.x += g * v.x; accS.y += g * v.y; accS.z += g * v.z; accS.w += g * v.w;
    }
    int ob = startO[node], oe = startO[node + 1];
    for (int i = ob; i < oe; i++) {
        int e = listO[i];
        float g = gate_po[e];
        int c = c_idx[e];
        float4 v = phra4[(size_t)c * 256 + t];
        accO.x += g * v.x; accO.y += g * v.y; accO.z += g * v.z; accO.w += g * v.w;
    }
    int cs = se - sb; if (cs < 1) cs = 1;
    int co = oe - ob; if (co < 1) co = 1;
    float is = 0.5f / (float)cs;
    float io = 0.5f / (float)co;
    float4 m;
    m.x = accS.x * is + accO.x * io;
    m.y = accS.y * is + accO.y * io;
    m.z = accS.z * is + accO.z * io;
    m.w = accS.w * is + accO.w * io;
    msg4[(size_t)node * 256 + t] = m;
}

// phra side: msg_p = 0.5*(sum gate_op*inst[o] + sum gate_sp*inst[s]) / cntC
__global__ __launch_bounds__(256) void seg_phra_kernel(
        const float4* __restrict__ inst4,
        const int* __restrict__ s_idx, const int* __restrict__ o_idx,
        const float* __restrict__ gates,
        const int* __restrict__ listC, const int* __restrict__ startC,
        float4* __restrict__ msg4) {
    int p = blockIdx.x, t = threadIdx.x;
    const float* gate_op = gates + 2 * EE;
    const float* gate_sp = gates + 3 * EE;
    float4 acc = make_float4(0.f, 0.f, 0.f, 0.f);
    int cb = startC[p], ce = startC[p + 1];
    for (int i = cb; i < ce; i++) {
        int e = listC[i];
        float go = gate_op[e], gs = gate_sp[e];
        int o = o_idx[e], s = s_idx[e];
        float4 vo = inst4[(size_t)o * 256 + t];
        float4 vs = inst4[(size_t)s * 256 + t];
        acc.x += go * vo.x + gs * vs.x;
        acc.y += go * vo.y + gs * vs.y;
        acc.z += go * vo.z + gs * vs.z;
        acc.w += go * vo.w + gs * vs.w;
    }
    int cc = ce - cb; if (cc < 1) cc = 1;
    float inv = 0.5f / (float)cc;
    float4 m;
    m.x = acc.x * inv; m.y = acc.y * inv; m.z = acc.z * inv; m.w = acc.w * inv;
    msg4[(size_t)p * 256 + t] = m;
}

// ---------------------------------------------------------------------------
// Fused refine: out = msg + relu(msg@W1 + b1) + relu(feat@W2 + b2)
// 128x128 tile, 256 threads, 8x8 microtile, two sequential K=1024 passes.
__device__ __forceinline__ void gemm_pass(const float* __restrict__ A, const float* __restrict__ B,
                                          float (&acc)[8][8], float (&As)[16][128],
                                          float (&Bs)[16][128], int bm, int bn, int t) {
    int tx = t & 15, ty = t >> 4;
    for (int k0 = 0; k0 < DD; k0 += 16) {
        #pragma unroll
        for (int r = 0; r < 2; r++) {
            int idx = t + r * 256;
            int row = idx >> 2, c4 = idx & 3;
            float4 av = *(const float4*)&A[(size_t)(bm + row) * DD + k0 + c4 * 4];
            As[c4 * 4 + 0][row] = av.x; As[c4 * 4 + 1][row] = av.y;
            As[c4 * 4 + 2][row] = av.z; As[c4 * 4 + 3][row] = av.w;
            int brow = idx >> 5, bc4 = idx & 31;
            *(float4*)&Bs[brow][bc4 * 4] =
                *(const float4*)&B[(size_t)(k0 + brow) * DD + bn + bc4 * 4];
        }
        __syncthreads();
        #pragma unroll
        for (int k = 0; k < 16; k++) {
            float a[8], b[8];
            *(float4*)&a[0] = *(const float4*)&As[k][ty * 8];
            *(float4*)&a[4] = *(const float4*)&As[k][ty * 8 + 4];
            *(float4*)&b[0] = *(const float4*)&Bs[k][tx * 8];
            *(float4*)&b[4] = *(const float4*)&Bs[k][tx * 8 + 4];
            #pragma unroll
            for (int i = 0; i < 8; i++)
                #pragma unroll
                for (int j = 0; j < 8; j++)
                    acc[i][j] = fmaf(a[i], b[j], acc[i][j]);
        }
        __syncthreads();
    }
}

__global__ __launch_bounds__(256) void refine_gemm_kernel(
        const float* __restrict__ Amsg, const float* __restrict__ Afeat,
        const float* __restrict__ W1, const float* __restrict__ b1,
        const float* __restrict__ W2, const float* __restrict__ b2,
        float* __restrict__ out) {
    __shared__ float As[16][128];
    __shared__ float Bs[16][128];
    int bm = blockIdx.x * 128, bn = blockIdx.y * 128;
    int t = threadIdx.x;
    float acc1[8][8] = {};
    float acc2[8][8] = {};
    gemm_pass(Amsg, W1, acc1, As, Bs, bm, bn, t);
    gemm_pass(Afeat, W2, acc2, As, Bs, bm, bn, t);
    int tx = t & 15, ty = t >> 4;
    #pragma unroll
    for (int i = 0; i < 8; i++) {
        int row = bm + ty * 8 + i;
        #pragma unroll
        for (int j4 = 0; j4 < 2; j4++) {
            int col = bn + tx * 8 + j4 * 4;
            float4 m  = *(const float4*)&Amsg[(size_t)row * DD + col];
            float4 v1 = *(const float4*)&b1[col];
            float4 v2 = *(const float4*)&b2[col];
            float4 o;
            o.x = m.x + fmaxf(acc1[i][j4*4+0] + v1.x, 0.f) + fmaxf(acc2[i][j4*4+0] + v2.x, 0.f);
            o.y = m.y + fmaxf(acc1[i][j4*4+1] + v1.y, 0.f) + fmaxf(acc2[i][j4*4+1] + v2.y, 0.f);
            o.z = m.z + fmaxf(acc1[i][j4*4+2] + v1.z, 0.f) + fmaxf(acc2[i][j4*4+2] + v2.z, 0.f);
            o.w = m.w + fmaxf(acc1[i][j4*4+3] + v1.w, 0.f) + fmaxf(acc2[i][j4*4+3] + v2.w, 0.f);
            *(float4*)&out[(size_t)row * DD + col] = o;
        }
    }
}

// ---------------------------------------------------------------------------
extern "C" void kernel_launch(void* const* d_in, const int* in_sizes, int n_in,
                              void* d_out, int out_size, void* d_ws, size_t ws_size,
                              hipStream_t stream) {
    (void)in_sizes; (void)n_in; (void)out_size; (void)ws_size;
    const float* inst_feat = (const float*)d_in[0];
    const float* phra_feat = (const float*)d_in[1];
    const int*   conn      = (const int*)d_in[2];
    const int*   clu       = (const int*)d_in[3];
    const float* psW = (const float*)d_in[4];  const float* psB = (const float*)d_in[5];
    const float* poW = (const float*)d_in[6];  const float* poB = (const float*)d_in[7];
    const float* opW = (const float*)d_in[8];  const float* opB = (const float*)d_in[9];
    const float* spW = (const float*)d_in[10]; const float* spB = (const float*)d_in[11];
    const float* iw1W = (const float*)d_in[12]; const float* iw1B = (const float*)d_in[13];
    const float* iw2W = (const float*)d_in[14]; const float* iw2B = (const float*)d_in[15];
    const float* pw1W = (const float*)d_in[16]; const float* pw1B = (const float*)d_in[17];
    const float* pw2W = (const float*)d_in[18]; const float* pw2B = (const float*)d_in[19];
    const int* s_idx = conn;
    const int* o_idx = conn + EE;

    char* ws = (char*)d_ws;
    size_t off = 0;
    auto alloc = [&](size_t bytes) {
        char* p = ws + off;
        off += (bytes + 255) & ~(size_t)255;
        return p;
    };
    float* Ti      = (float*)alloc((size_t)NN * G4 * 4);
    float* Tp      = (float*)alloc((size_t)PP * G4 * 4);
    float* Wi      = (float*)alloc((size_t)DD * G4 * 4);
    float* Wp      = (float*)alloc((size_t)DD * G4 * 4);
    float* biascat = (float*)alloc(G4 * 4);
    float* gates   = (float*)alloc((size_t)4 * EE * 4);
    int* cntBlock  = (int*)alloc((size_t)(2 * (NN + NN + PP)) * 4);
    int* cntS = cntBlock;      int* cntO = cntS + NN;  int* cntC = cntO + NN;
    int* curS = cntC + PP;     int* curO = curS + NN;  int* curC = curO + NN;
    int* startS = (int*)alloc((NN + 1) * 4);
    int* startO = (int*)alloc((NN + 1) * 4);
    int* startC = (int*)alloc((PP + 1) * 4);
    int* listS  = (int*)alloc((size_t)EE * 4);
    int* listO  = (int*)alloc((size_t)EE * 4);
    int* listC  = (int*)alloc((size_t)EE * 4);
    float* imsg = (float*)alloc((size_t)NN * DD * 4);
    float* pmsg = (float*)alloc((size_t)PP * DD * 4);

    float* inst_out = (float*)d_out;
    float* phra_out = inst_out + (size_t)NN * DD;

    hipMemsetAsync(cntBlock, 0, (size_t)(2 * (NN + NN + PP)) * 4, stream);

    pack_kernel<<<(DD * OUTF) / 256, 256, 0, stream>>>(psW, poW, opW, spW,
                                                       psB, poB, opB, spB,
                                                       Wi, Wp, biascat);
    dim3 tgI(NN / 64, G4 / 64);
    table_gemm_kernel<<<tgI, 256, 0, stream>>>(inst_feat, Wi, nullptr, Ti);
    dim3 tgP(PP / 64, G4 / 64);
    table_gemm_kernel<<<tgP, 256, 0, stream>>>(phra_feat, Wp, biascat, Tp);

    hist_kernel<<<EE / 256, 256, 0, stream>>>(s_idx, o_idx, clu, cntS, cntO, cntC);
    scan_kernel<<<1, 1024, 0, stream>>>(cntS, startS, NN);
    scan_kernel<<<1, 1024, 0, stream>>>(cntO, startO, NN);
    scan_kernel<<<1, 1024, 0, stream>>>(cntC, startC, PP);
    scatter_kernel<<<EE / 256, 256, 0, stream>>>(s_idx, o_idx, clu, startS, startO, startC,
                                                 curS, curO, curC, listS, listO, listC);

    gate_kernel<<<(EE * 64) / 256, 256, 0, stream>>>(s_idx, o_idx, clu, Ti, Tp, gates);

    seg_inst_kernel<<<NN, 256, 0, stream>>>((const float4*)phra_feat, clu, gates,
                                            listS, startS, listO, startO, (float4*)imsg);
    seg_phra_kernel<<<PP, 256, 0, stream>>>((const float4*)inst_feat, s_idx, o_idx, gates,
                                            listC, startC, (float4*)pmsg);

    dim3 rgI(NN / 128, DD / 128);
    refine_gemm_kernel<<<rgI, 256, 0, stream>>>(imsg, inst_feat, iw1W, iw1B, iw2W, iw2B, inst_out);
    dim3 rgP(PP / 128, DD / 128);
    refine_gemm_kernel<<<rgP, 256, 0, stream>>>(pmsg, phra_feat, pw1W, pw1B, pw2W, pw2B, phra_out);
}

// Round 2
// 323.238 us; speedup vs baseline: 2.7700x; 2.7700x over previous
//
#include <hip/hip_runtime.h>
#include <math.h>

// Problem constants (fixed by the reference)
constexpr int NN  = 4096;   // instances
constexpr int PP  = 2048;   // phrases
constexpr int EE  = 65536;  // edges
constexpr int DD  = 1024;   // feature dim
constexpr int OUTF = 128;   // gate MLP out dim
constexpr int G4  = 512;    // 4 gates * 128

typedef __attribute__((ext_vector_type(8))) short short8v;
typedef __attribute__((ext_vector_type(4))) float f32x4;

__device__ __forceinline__ float sigmoid_relu(float z) {
    z = fmaxf(z, 0.0f);
    return 1.0f / (1.0f + __expf(-z));
}
__device__ __forceinline__ float b2f(ushort u) {
    return __uint_as_float(((unsigned int)u) << 16);
}
__device__ __forceinline__ ushort f2b(float f) {  // RNE
    unsigned int x = __float_as_uint(f);
    return (ushort)((x + 0x7fffu + ((x >> 16) & 1u)) >> 16);
}

#define GLD16(gptr, lptr) \
    __builtin_amdgcn_global_load_lds((__attribute__((address_space(1))) const void*)(gptr), \
                                     (__attribute__((address_space(3))) void*)(lptr), 16, 0, 0)

// ---------------------------------------------------------------------------
// f32 -> bf16 elementwise (4 per thread)
__global__ __launch_bounds__(256) void f2b_kernel(const float* __restrict__ in,
                                                  ushort* __restrict__ out, int n4) {
    int i = blockIdx.x * 256 + threadIdx.x;
    if (i >= n4) return;
    float4 v = ((const float4*)in)[i];
    ushort4 u;
    u.x = f2b(v.x); u.y = f2b(v.y); u.z = f2b(v.z); u.w = f2b(v.w);
    ((ushort4*)out)[i] = u;
}

// ---------------------------------------------------------------------------
// Pack gate weights, TRANSPOSED + bf16: WiT/WpT [512][1024]; biascat f32 [512].
__global__ __launch_bounds__(256) void pack_kernel(
        const float* __restrict__ psW, const float* __restrict__ poW,
        const float* __restrict__ opW, const float* __restrict__ spW,
        const float* __restrict__ psB, const float* __restrict__ poB,
        const float* __restrict__ opB, const float* __restrict__ spB,
        ushort* __restrict__ WiT, ushort* __restrict__ WpT,
        float* __restrict__ biascat) {
    int idx = blockIdx.x * 256 + threadIdx.x;
    if (idx >= G4 * DD) return;
    int n = idx >> 10;      // output row (gate-col) 0..511
    int k = idx & 1023;     // input feature 0..1023
    int g = n >> 7, j = n & 127;
    float wi, wp;
    if (g == 0)      { wi = psW[(size_t)(DD + k) * OUTF + j]; wp = psW[(size_t)k * OUTF + j]; }
    else if (g == 1) { wi = poW[(size_t)(DD + k) * OUTF + j]; wp = poW[(size_t)k * OUTF + j]; }
    else if (g == 2) { wi = opW[(size_t)k * OUTF + j];        wp = opW[(size_t)(DD + k) * OUTF + j]; }
    else             { wi = spW[(size_t)k * OUTF + j];        wp = spW[(size_t)(DD + k) * OUTF + j]; }
    WiT[idx] = f2b(wi);
    WpT[idx] = f2b(wp);
    if (idx < G4) {
        int gg = idx >> 7, jj = idx & 127;
        biascat[idx] = (gg == 0) ? psB[jj] : (gg == 1) ? poB[jj] : (gg == 2) ? opB[jj] : spB[jj];
    }
}

// ---------------------------------------------------------------------------
// Transpose-convert refine weights: W [1024][1024] f32 -> WT [1024][1024] bf16.
__global__ __launch_bounds__(256) void wtrans_kernel(const float* __restrict__ W,
                                                     ushort* __restrict__ WT) {
    __shared__ float tile[64][65];
    int k0 = blockIdx.x * 64, n0 = blockIdx.y * 64;
    int tx = threadIdx.x & 63, ty = threadIdx.x >> 6;  // 64 x 4
    #pragma unroll
    for (int i = 0; i < 64; i += 4)
        tile[ty + i][tx] = W[(size_t)(k0 + ty + i) * DD + n0 + tx];
    __syncthreads();
    #pragma unroll
    for (int i = 0; i < 64; i += 4)
        WT[(size_t)(n0 + ty + i) * DD + k0 + tx] = f2b(tile[tx][ty + i]);
}

// Fold gate bias into the phrase table (bf16 += f32)
__global__ __launch_bounds__(256) void biasadd_kernel(ushort* __restrict__ Tp,
                                                      const float* __restrict__ biascat) {
    int idx = blockIdx.x * 256 + threadIdx.x;
    if (idx >= PP * G4) return;
    Tp[idx] = f2b(b2f(Tp[idx]) + biascat[idx & (G4 - 1)]);
}

// ---------------------------------------------------------------------------
// MFMA GEMM: C[M][N] = A[M][1024] @ BT[N][1024]^T   (bf16 in, f32 or bf16 out)
// 128x128 tile, BK=64, 4 waves, 16x16x32 MFMA, global_load_lds staging,
// XOR-swizzled LDS (chunk16 ^= row&7) per guide G4/rule21.
template<bool BF16OUT>
__global__ __launch_bounds__(256) void mfma_gemm_bt(
        const ushort* __restrict__ A, const ushort* __restrict__ BT,
        void* __restrict__ Cv, int N) {
    constexpr int K = 1024;
    __shared__ ushort Asl[128 * 64];
    __shared__ ushort Bsl[128 * 64];
    const int t = threadIdx.x;
    const int bm = blockIdx.x * 128;
    const int bn = blockIdx.y * 128;
    const int lane = t & 63;
    const int w = t >> 6;
    const int wr = (w >> 1) * 64;
    const int wc = (w & 1) * 64;
    const int lr = lane & 15;
    const int lk = lane >> 4;
    f32x4 acc[4][4] = {};

    for (int k0 = 0; k0 < K; k0 += 64) {
        #pragma unroll
        for (int r = 0; r < 4; r++) {
            int ch = r * 256 + t;           // 16B chunk id, 0..1023
            int row = ch >> 3;              // tile row 0..127
            int sw = ((ch & 7) ^ (row & 7)) << 3;  // pre-swizzled source elem offset
            GLD16(A + (size_t)(bm + row) * K + k0 + sw, &Asl[ch * 8]);
            GLD16(BT + (size_t)(bn + row) * K + k0 + sw, &Bsl[ch * 8]);
        }
        __syncthreads();
        #pragma unroll
        for (int kk = 0; kk < 2; kk++) {
            int ch16 = kk * 4 + lk;         // 16B chunk col within row
            short8v a[4], b[4];
            #pragma unroll
            for (int m = 0; m < 4; m++) {
                int ra = wr + m * 16 + lr;
                a[m] = *(const short8v*)&Asl[ra * 64 + ((ch16 ^ (ra & 7)) << 3)];
                int rb = wc + m * 16 + lr;
                b[m] = *(const short8v*)&Bsl[rb * 64 + ((ch16 ^ (rb & 7)) << 3)];
            }
            #pragma unroll
            for (int m = 0; m < 4; m++)
                #pragma unroll
                for (int n = 0; n < 4; n++)
                    acc[m][n] = __builtin_amdgcn_mfma_f32_16x16x32_bf16(a[m], b[n], acc[m][n], 0, 0, 0);
        }
        __syncthreads();
    }
    // C/D layout: col = lane&15, row = (lane>>4)*4 + reg   [guide §3, m89-verified]
    #pragma unroll
    for (int m = 0; m < 4; m++) {
        int row = bm + wr + m * 16 + lk * 4;
        #pragma unroll
        for (int n = 0; n < 4; n++) {
            int col = bn + wc + n * 16 + lr;
            #pragma unroll
            for (int r = 0; r < 4; r++) {
                float v = acc[m][n][r];
                if (BF16OUT) ((ushort*)Cv)[(size_t)(row + r) * N + col] = f2b(v);
                else         ((float*)Cv)[(size_t)(row + r) * N + col] = v;
            }
        }
    }
}

// ---------------------------------------------------------------------------
// Per-edge gates from bf16 tables (bias pre-folded into Tp).  One wave/edge.
__global__ __launch_bounds__(256) void gate_kernel(
        const int* __restrict__ s_idx, const int* __restrict__ o_idx,
        const int* __restrict__ c_idx,
        const ushort* __restrict__ Ti, const ushort* __restrict__ Tp,
        float* __restrict__ gates) {
    int gid = blockIdx.x * 256 + threadIdx.x;
    int e = gid >> 6, lane = gid & 63;
    if (e >= EE) return;
    int s = s_idx[e], o = o_idx[e], c = c_idx[e];
    const unsigned int* tpc = (const unsigned int*)(Tp + (size_t)c * G4);
    const unsigned int* tis = (const unsigned int*)(Ti + (size_t)s * G4);
    const unsigned int* tio = (const unsigned int*)(Ti + (size_t)o * G4);
    auto pairSig = [](unsigned int a, unsigned int b) {
        float lo = __uint_as_float(a << 16) + __uint_as_float(b << 16);
        float hi = __uint_as_float(a & 0xffff0000u) + __uint_as_float(b & 0xffff0000u);
        return sigmoid_relu(lo) + sigmoid_relu(hi);
    };
    float s0 = pairSig(tpc[lane],       tis[lane]);
    float s1 = pairSig(tpc[64 + lane],  tio[64 + lane]);
    float s2 = pairSig(tpc[128 + lane], tio[128 + lane]);
    float s3 = pairSig(tpc[192 + lane], tis[192 + lane]);
    #pragma unroll
    for (int off = 32; off; off >>= 1) {
        s0 += __shfl_xor(s0, off);
        s1 += __shfl_xor(s1, off);
        s2 += __shfl_xor(s2, off);
        s3 += __shfl_xor(s3, off);
    }
    if (lane == 0) {
        const float inv = 1.0f / 128.0f;
        gates[e]          = s0 * inv;
        gates[EE + e]     = s1 * inv;
        gates[2 * EE + e] = s2 * inv;
        gates[3 * EE + e] = s3 * inv;
    }
}

// ---------------------------------------------------------------------------
// Counting sort machinery (unchanged from R1 — proven)
__global__ void hist_kernel(const int* __restrict__ s_idx, const int* __restrict__ o_idx,
                            const int* __restrict__ c_idx,
                            int* cntS, int* cntO, int* cntC) {
    int e = blockIdx.x * blockDim.x + threadIdx.x;
    if (e >= EE) return;
    atomicAdd(&cntS[s_idx[e]], 1);
    atomicAdd(&cntO[o_idx[e]], 1);
    atomicAdd(&cntC[c_idx[e]], 1);
}

__global__ __launch_bounds__(1024) void scan_kernel(const int* __restrict__ cnt,
                                                    int* __restrict__ start, int n) {
    __shared__ int sh[1024];
    int t = threadIdx.x;
    int per = n >> 10;
    int base = t * per;
    int s = 0;
    for (int i = 0; i < per; i++) s += cnt[base + i];
    sh[t] = s;
    __syncthreads();
    for (int off = 1; off < 1024; off <<= 1) {
        int v = (t >= off) ? sh[t - off] : 0;
        __syncthreads();
        sh[t] += v;
        __syncthreads();
    }
    int ex = (t == 0) ? 0 : sh[t - 1];
    for (int i = 0; i < per; i++) { start[base + i] = ex; ex += cnt[base + i]; }
    if (t == 1023) start[n] = ex;
}

__global__ void scatter_kernel(const int* __restrict__ s_idx, const int* __restrict__ o_idx,
                               const int* __restrict__ c_idx,
                               const int* __restrict__ startS, const int* __restrict__ startO,
                               const int* __restrict__ startC,
                               int* curS, int* curO, int* curC,
                               int* listS, int* listO, int* listC) {
    int e = blockIdx.x * blockDim.x + threadIdx.x;
    if (e >= EE) return;
    int s = s_idx[e];
    listS[startS[s] + atomicAdd(&curS[s], 1)] = e;
    int o = o_idx[e];
    listO[startO[o] + atomicAdd(&curO[o], 1)] = e;
    int c = c_idx[e];
    listC[startC[c] + atomicAdd(&curC[c], 1)] = e;
}

// ---------------------------------------------------------------------------
// Segment means (bf16 features in, bf16 msg out).
__global__ __launch_bounds__(256) void seg_inst_kernel(
        const ushort* __restrict__ phraB, const int* __restrict__ c_idx,
        const float* __restrict__ gates,
        const int* __restrict__ listS, const int* __restrict__ startS,
        const int* __restrict__ listO, const int* __restrict__ startO,
        ushort* __restrict__ msgB) {
    int node = blockIdx.x, t = threadIdx.x;
    const float* gps = gates;
    const float* gpo = gates + EE;
    float aS0 = 0.f, aS1 = 0.f, aS2 = 0.f, aS3 = 0.f;
    float aO0 = 0.f, aO1 = 0.f, aO2 = 0.f, aO3 = 0.f;
    int sb = startS[node], se = startS[node + 1];
    for (int i = sb; i < se; i++) {
        int e = listS[i];
        float g = gps[e];
        int c = c_idx[e];
        uint2 v = *(const uint2*)&phraB[(size_t)c * DD + t * 4];
        aS0 += g * __uint_as_float(v.x << 16);
        aS1 += g * __uint_as_float(v.x & 0xffff0000u);
        aS2 += g * __uint_as_float(v.y << 16);
        aS3 += g * __uint_as_float(v.y & 0xffff0000u);
    }
    int ob = startO[node], oe = startO[node + 1];
    for (int i = ob; i < oe; i++) {
        int e = listO[i];
        float g = gpo[e];
        int c = c_idx[e];
        uint2 v = *(const uint2*)&phraB[(size_t)c * DD + t * 4];
        aO0 += g * __uint_as_float(v.x << 16);
        aO1 += g * __uint_as_float(v.x & 0xffff0000u);
        aO2 += g * __uint_as_float(v.y << 16);
        aO3 += g * __uint_as_float(v.y & 0xffff0000u);
    }
    int cs = se - sb; if (cs < 1) cs = 1;
    int co = oe - ob; if (co < 1) co = 1;
    float is = 0.5f / (float)cs, io = 0.5f / (float)co;
    ushort4 u;
    u.x = f2b(aS0 * is + aO0 * io);
    u.y = f2b(aS1 * is + aO1 * io);
    u.z = f2b(aS2 * is + aO2 * io);
    u.w = f2b(aS3 * is + aO3 * io);
    *(ushort4*)&msgB[(size_t)node * DD + t * 4] = u;
}

__global__ __launch_bounds__(256) void seg_phra_kernel(
        const ushort* __restrict__ instB,
        const int* __restrict__ s_idx, const int* __restrict__ o_idx,
        const float* __restrict__ gates,
        const int* __restrict__ listC, const int* __restrict__ startC,
        ushort* __restrict__ msgB) {
    int p = blockIdx.x, t = threadIdx.x;
    const float* gop = gates + 2 * EE;
    const float* gsp = gates + 3 * EE;
    float a0 = 0.f, a1 = 0.f, a2 = 0.f, a3 = 0.f;
    int cb = startC[p], ce = startC[p + 1];
    for (int i = cb; i < ce; i++) {
        int e = listC[i];
        float go = gop[e], gs = gsp[e];
        int o = o_idx[e], s = s_idx[e];
        uint2 vo = *(const uint2*)&instB[(size_t)o * DD + t * 4];
        uint2 vs = *(const uint2*)&instB[(size_t)s * DD + t * 4];
        a0 += go * __uint_as_float(vo.x << 16) + gs * __uint_as_float(vs.x << 16);
        a1 += go * __uint_as_float(vo.x & 0xffff0000u) + gs * __uint_as_float(vs.x & 0xffff0000u);
        a2 += go * __uint_as_float(vo.y << 16) + gs * __uint_as_float(vs.y << 16);
        a3 += go * __uint_as_float(vo.y & 0xffff0000u) + gs * __uint_as_float(vs.y & 0xffff0000u);
    }
    int cc = ce - cb; if (cc < 1) cc = 1;
    float inv = 0.5f / (float)cc;
    ushort4 u;
    u.x = f2b(a0 * inv); u.y = f2b(a1 * inv); u.z = f2b(a2 * inv); u.w = f2b(a3 * inv);
    *(ushort4*)&msgB[(size_t)p * DD + t * 4] = u;
}

// ---------------------------------------------------------------------------
// Epilogue: out = msg + relu(g1 + b1) + relu(g2 + b2)
__global__ __launch_bounds__(256) void refine_epi_kernel(
        const ushort* __restrict__ msgB, const float* __restrict__ g1,
        const float* __restrict__ b1, const float* __restrict__ g2,
        const float* __restrict__ b2, float* __restrict__ out, int total4) {
    int i = blockIdx.x * 256 + threadIdx.x;
    if (i >= total4) return;
    int col4 = (i & 255) * 4;
    float4 x1 = ((const float4*)g1)[i];
    float4 x2 = ((const float4*)g2)[i];
    float4 vb1 = *(const float4*)&b1[col4];
    float4 vb2 = *(const float4*)&b2[col4];
    uint2 mu = ((const uint2*)msgB)[i];
    float m0 = __uint_as_float(mu.x << 16);
    float m1 = __uint_as_float(mu.x & 0xffff0000u);
    float m2 = __uint_as_float(mu.y << 16);
    float m3 = __uint_as_float(mu.y & 0xffff0000u);
    float4 o;
    o.x = m0 + fmaxf(x1.x + vb1.x, 0.f) + fmaxf(x2.x + vb2.x, 0.f);
    o.y = m1 + fmaxf(x1.y + vb1.y, 0.f) + fmaxf(x2.y + vb2.y, 0.f);
    o.z = m2 + fmaxf(x1.z + vb1.z, 0.f) + fmaxf(x2.z + vb2.z, 0.f);
    o.w = m3 + fmaxf(x1.w + vb1.w, 0.f) + fmaxf(x2.w + vb2.w, 0.f);
    ((float4*)out)[i] = o;
}

// ---------------------------------------------------------------------------
extern "C" void kernel_launch(void* const* d_in, const int* in_sizes, int n_in,
                              void* d_out, int out_size, void* d_ws, size_t ws_size,
                              hipStream_t stream) {
    (void)in_sizes; (void)n_in; (void)out_size; (void)ws_size;
    const float* inst_feat = (const float*)d_in[0];
    const float* phra_feat = (const float*)d_in[1];
    const int*   conn      = (const int*)d_in[2];
    const int*   clu       = (const int*)d_in[3];
    const float* psW = (const float*)d_in[4];  const float* psB = (const float*)d_in[5];
    const float* poW = (const float*)d_in[6];  const float* poB = (const float*)d_in[7];
    const float* opW = (const float*)d_in[8];  const float* opB = (const float*)d_in[9];
    const float* spW = (const float*)d_in[10]; const float* spB = (const float*)d_in[11];
    const float* iw1W = (const float*)d_in[12]; const float* iw1B = (const float*)d_in[13];
    const float* iw2W = (const float*)d_in[14]; const float* iw2B = (const float*)d_in[15];
    const float* pw1W = (const float*)d_in[16]; const float* pw1B = (const float*)d_in[17];
    const float* pw2W = (const float*)d_in[18]; const float* pw2B = (const float*)d_in[19];
    const int* s_idx = conn;
    const int* o_idx = conn + EE;

    char* ws = (char*)d_ws;
    size_t off = 0;
    auto alloc = [&](size_t bytes) {
        char* p = ws + off;
        off += (bytes + 255) & ~(size_t)255;
        return p;
    };
    ushort* instB = (ushort*)alloc((size_t)NN * DD * 2);
    ushort* phraB = (ushort*)alloc((size_t)PP * DD * 2);
    ushort* WiT   = (ushort*)alloc((size_t)G4 * DD * 2);
    ushort* WpT   = (ushort*)alloc((size_t)G4 * DD * 2);
    ushort* iw1T  = (ushort*)alloc((size_t)DD * DD * 2);
    ushort* iw2T  = (ushort*)alloc((size_t)DD * DD * 2);
    ushort* pw1T  = (ushort*)alloc((size_t)DD * DD * 2);
    ushort* pw2T  = (ushort*)alloc((size_t)DD * DD * 2);
    float* biascat = (float*)alloc(G4 * 4);
    ushort* TiB   = (ushort*)alloc((size_t)NN * G4 * 2);
    ushort* TpB   = (ushort*)alloc((size_t)PP * G4 * 2);
    float* gates  = (float*)alloc((size_t)4 * EE * 4);
    int* cntBlock = (int*)alloc((size_t)(2 * (NN + NN + PP)) * 4);
    int* cntS = cntBlock;      int* cntO = cntS + NN;  int* cntC = cntO + NN;
    int* curS = cntC + PP;     int* curO = curS + NN;  int* curC = curO + NN;
    int* startS = (int*)alloc((NN + 1) * 4);
    int* startO = (int*)alloc((NN + 1) * 4);
    int* startC = (int*)alloc((PP + 1) * 4);
    int* listS  = (int*)alloc((size_t)EE * 4);
    int* listO  = (int*)alloc((size_t)EE * 4);
    int* listC  = (int*)alloc((size_t)EE * 4);
    ushort* imsgB = (ushort*)alloc((size_t)NN * DD * 2);
    ushort* pmsgB = (ushort*)alloc((size_t)PP * DD * 2);
    float* G1i = (float*)alloc((size_t)NN * DD * 4);
    float* G2i = (float*)alloc((size_t)NN * DD * 4);
    float* G1p = (float*)alloc((size_t)PP * DD * 4);
    float* G2p = (float*)alloc((size_t)PP * DD * 4);

    float* inst_out = (float*)d_out;
    float* phra_out = inst_out + (size_t)NN * DD;

    hipMemsetAsync(cntBlock, 0, (size_t)(2 * (NN + NN + PP)) * 4, stream);

    // Conversions / packing
    f2b_kernel<<<(NN * DD / 4 + 255) / 256, 256, 0, stream>>>(inst_feat, instB, NN * DD / 4);
    f2b_kernel<<<(PP * DD / 4 + 255) / 256, 256, 0, stream>>>(phra_feat, phraB, PP * DD / 4);
    pack_kernel<<<(G4 * DD) / 256, 256, 0, stream>>>(psW, poW, opW, spW, psB, poB, opB, spB,
                                                     WiT, WpT, biascat);
    dim3 wt(DD / 64, DD / 64);
    wtrans_kernel<<<wt, 256, 0, stream>>>(iw1W, iw1T);
    wtrans_kernel<<<wt, 256, 0, stream>>>(iw2W, iw2T);
    wtrans_kernel<<<wt, 256, 0, stream>>>(pw1W, pw1T);
    wtrans_kernel<<<wt, 256, 0, stream>>>(pw2W, pw2T);

    // CSR build
    hist_kernel<<<EE / 256, 256, 0, stream>>>(s_idx, o_idx, clu, cntS, cntO, cntC);
    scan_kernel<<<1, 1024, 0, stream>>>(cntS, startS, NN);
    scan_kernel<<<1, 1024, 0, stream>>>(cntO, startO, NN);
    scan_kernel<<<1, 1024, 0, stream>>>(cntC, startC, PP);
    scatter_kernel<<<EE / 256, 256, 0, stream>>>(s_idx, o_idx, clu, startS, startO, startC,
                                                 curS, curO, curC, listS, listO, listC);

    // Gate tables (bf16 MFMA), bias folded into Tp
    mfma_gemm_bt<true><<<dim3(NN / 128, G4 / 128), 256, 0, stream>>>(instB, WiT, TiB, G4);
    mfma_gemm_bt<true><<<dim3(PP / 128, G4 / 128), 256, 0, stream>>>(phraB, WpT, TpB, G4);
    biasadd_kernel<<<(PP * G4) / 256, 256, 0, stream>>>(TpB, biascat);

    gate_kernel<<<(EE * 64) / 256, 256, 0, stream>>>(s_idx, o_idx, clu, TiB, TpB, gates);

    // Segment means
    seg_inst_kernel<<<NN, 256, 0, stream>>>(phraB, clu, gates, listS, startS, listO, startO, imsgB);
    seg_phra_kernel<<<PP, 256, 0, stream>>>(instB, s_idx, o_idx, gates, listC, startC, pmsgB);

    // Refine GEMMs (bf16 MFMA, f32 out)
    mfma_gemm_bt<false><<<dim3(NN / 128, DD / 128), 256, 0, stream>>>(imsgB, iw1T, G1i, DD);
    mfma_gemm_bt<false><<<dim3(NN / 128, DD / 128), 256, 0, stream>>>(instB, iw2T, G2i, DD);
    mfma_gemm_bt<false><<<dim3(PP / 128, DD / 128), 256, 0, stream>>>(pmsgB, pw1T, G1p, DD);
    mfma_gemm_bt<false><<<dim3(PP / 128, DD / 128), 256, 0, stream>>>(phraB, pw2T, G2p, DD);

    // Epilogues
    refine_epi_kernel<<<(NN * DD / 4) / 256, 256, 0, stream>>>(imsgB, G1i, iw1B, G2i, iw2B,
                                                               inst_out, NN * DD / 4);
    refine_epi_kernel<<<(PP * DD / 4) / 256, 256, 0, stream>>>(pmsgB, G1p, pw1B, G2p, pw2B,
                                                               phra_out, PP * DD / 4);
}

// Round 3
// 233.552 us; speedup vs baseline: 3.8337x; 1.3840x over previous
//
#include <hip/hip_runtime.h>
#include <math.h>

// Problem constants (fixed by the reference)
constexpr int NN  = 4096;   // instances
constexpr int PP  = 2048;   // phrases
constexpr int EE  = 65536;  // edges
constexpr int DD  = 1024;   // feature dim
constexpr int OUTF = 128;   // gate MLP out dim
constexpr int G4  = 512;    // 4 gates * 128

typedef __attribute__((ext_vector_type(8))) short short8v;
typedef __attribute__((ext_vector_type(4))) float f32x4;

__device__ __forceinline__ float sigmoid_relu(float z) {
    z = fmaxf(z, 0.0f);
    return 1.0f / (1.0f + __expf(-z));
}
__device__ __forceinline__ float b2f(ushort u) {
    return __uint_as_float(((unsigned int)u) << 16);
}
__device__ __forceinline__ ushort f2b(float f) {  // RNE
    unsigned int x = __float_as_uint(f);
    return (ushort)((x + 0x7fffu + ((x >> 16) & 1u)) >> 16);
}
__device__ __forceinline__ unsigned int pack2(float a, float b) {
    return (unsigned int)f2b(a) | ((unsigned int)f2b(b) << 16);
}

#define GLD16(gptr, lptr) \
    __builtin_amdgcn_global_load_lds((__attribute__((address_space(1))) const void*)(gptr), \
                                     (__attribute__((address_space(3))) void*)(lptr), 16, 0, 0)

// ---------------------------------------------------------------------------
// f32 -> bf16 for both feature arrays in one launch
__global__ __launch_bounds__(256) void f2b2_kernel(const float* __restrict__ a,
                                                   const float* __restrict__ b,
                                                   ushort* __restrict__ oa,
                                                   ushort* __restrict__ ob) {
    int i = blockIdx.x * 256 + threadIdx.x;
    constexpr int na4 = NN * DD / 4;
    constexpr int nb4 = PP * DD / 4;
    if (i < na4) {
        float4 v = ((const float4*)a)[i];
        ushort4 u; u.x = f2b(v.x); u.y = f2b(v.y); u.z = f2b(v.z); u.w = f2b(v.w);
        ((ushort4*)oa)[i] = u;
    } else if (i - na4 < nb4) {
        int j = i - na4;
        float4 v = ((const float4*)b)[j];
        ushort4 u; u.x = f2b(v.x); u.y = f2b(v.y); u.z = f2b(v.z); u.w = f2b(v.w);
        ((ushort4*)ob)[j] = u;
    }
}

// ---------------------------------------------------------------------------
// Pack gate weights, TRANSPOSED + bf16: WiT/WpT [512][1024]; biascat f32 [512].
__global__ __launch_bounds__(256) void pack_kernel(
        const float* __restrict__ psW, const float* __restrict__ poW,
        const float* __restrict__ opW, const float* __restrict__ spW,
        const float* __restrict__ psB, const float* __restrict__ poB,
        const float* __restrict__ opB, const float* __restrict__ spB,
        ushort* __restrict__ WiT, ushort* __restrict__ WpT,
        float* __restrict__ biascat) {
    int idx = blockIdx.x * 256 + threadIdx.x;
    if (idx >= G4 * DD) return;
    int n = idx >> 10;      // output row (gate-col) 0..511
    int k = idx & 1023;     // input feature 0..1023
    int g = n >> 7, j = n & 127;
    float wi, wp;
    if (g == 0)      { wi = psW[(size_t)(DD + k) * OUTF + j]; wp = psW[(size_t)k * OUTF + j]; }
    else if (g == 1) { wi = poW[(size_t)(DD + k) * OUTF + j]; wp = poW[(size_t)k * OUTF + j]; }
    else if (g == 2) { wi = opW[(size_t)k * OUTF + j];        wp = opW[(size_t)(DD + k) * OUTF + j]; }
    else             { wi = spW[(size_t)k * OUTF + j];        wp = spW[(size_t)(DD + k) * OUTF + j]; }
    WiT[idx] = f2b(wi);
    WpT[idx] = f2b(wp);
    if (idx < G4) {
        int gg = idx >> 7, jj = idx & 127;
        biascat[idx] = (gg == 0) ? psB[jj] : (gg == 1) ? poB[jj] : (gg == 2) ? opB[jj] : spB[jj];
    }
}

// ---------------------------------------------------------------------------
// Transpose-convert all 4 refine weights in one launch (blockIdx.z selects).
__global__ __launch_bounds__(256) void wtrans4_kernel(
        const float* __restrict__ W0, const float* __restrict__ W1,
        const float* __restrict__ W2, const float* __restrict__ W3,
        ushort* __restrict__ T0, ushort* __restrict__ T1,
        ushort* __restrict__ T2, ushort* __restrict__ T3) {
    const float* W; ushort* T;
    switch (blockIdx.z) {
        case 0:  W = W0; T = T0; break;
        case 1:  W = W1; T = T1; break;
        case 2:  W = W2; T = T2; break;
        default: W = W3; T = T3; break;
    }
    __shared__ float tile[64][65];
    int k0 = blockIdx.x * 64, n0 = blockIdx.y * 64;
    int tx = threadIdx.x & 63, ty = threadIdx.x >> 6;  // 64 x 4
    #pragma unroll
    for (int i = 0; i < 64; i += 4)
        tile[ty + i][tx] = W[(size_t)(k0 + ty + i) * DD + n0 + tx];
    __syncthreads();
    #pragma unroll
    for (int i = 0; i < 64; i += 4)
        T[(size_t)(n0 + ty + i) * DD + k0 + tx] = f2b(tile[tx][ty + i]);
}

// ---------------------------------------------------------------------------
// Shared MFMA GEMM core: acc += A[bm..bm+128][0..1024] @ BT[bn..bn+128][0..1024]^T
// 128x128 tile, BK=64, 4 waves, 16x16x32 MFMA, global_load_lds, XOR-swizzled LDS.
__device__ __forceinline__ void gemm_core(const ushort* __restrict__ A,
                                          const ushort* __restrict__ BT,
                                          ushort* Asl, ushort* Bsl,
                                          f32x4 (&acc)[4][4], int bm, int bn, int t) {
    const int lane = t & 63, w = t >> 6;
    const int wr = (w >> 1) * 64, wc = (w & 1) * 64;
    const int lr = lane & 15, lk = lane >> 4;
    for (int k0 = 0; k0 < DD; k0 += 64) {
        #pragma unroll
        for (int r = 0; r < 4; r++) {
            int ch = r * 256 + t;                   // 16B chunk id, 0..1023
            int row = ch >> 3;                      // tile row 0..127
            int sw = ((ch & 7) ^ (row & 7)) << 3;   // pre-swizzled source elem offset
            GLD16(A + (size_t)(bm + row) * DD + k0 + sw, &Asl[ch * 8]);
            GLD16(BT + (size_t)(bn + row) * DD + k0 + sw, &Bsl[ch * 8]);
        }
        __syncthreads();
        #pragma unroll
        for (int kk = 0; kk < 2; kk++) {
            int ch16 = kk * 4 + lk;
            short8v a[4], b[4];
            #pragma unroll
            for (int m = 0; m < 4; m++) {
                int ra = wr + m * 16 + lr;
                a[m] = *(const short8v*)&Asl[ra * 64 + ((ch16 ^ (ra & 7)) << 3)];
                int rb = wc + m * 16 + lr;
                b[m] = *(const short8v*)&Bsl[rb * 64 + ((ch16 ^ (rb & 7)) << 3)];
            }
            #pragma unroll
            for (int m = 0; m < 4; m++)
                #pragma unroll
                for (int n = 0; n < 4; n++)
                    acc[m][n] = __builtin_amdgcn_mfma_f32_16x16x32_bf16(a[m], b[n], acc[m][n], 0, 0, 0);
        }
        __syncthreads();
    }
}

// ---------------------------------------------------------------------------
// Gate tables for inst AND phra in one launch. bf16 out; bias folded (phra only).
__global__ __launch_bounds__(256) void mfma_tables_kernel(
        const ushort* __restrict__ instB, const ushort* __restrict__ WiT,
        const ushort* __restrict__ phraB, const ushort* __restrict__ WpT,
        const float* __restrict__ biascat,
        ushort* __restrict__ TiB, ushort* __restrict__ TpB) {
    __shared__ ushort Asl[128 * 64];
    __shared__ ushort Bsl[128 * 64];
    const ushort *A, *BT; ushort* C; const float* bias;
    int bx = blockIdx.x;
    if (bx < NN / 128) { A = instB; BT = WiT; C = TiB; bias = nullptr; }
    else { bx -= NN / 128; A = phraB; BT = WpT; C = TpB; bias = biascat; }
    int bm = bx * 128, bn = blockIdx.y * 128;
    int t = threadIdx.x;
    f32x4 acc[4][4] = {};
    gemm_core(A, BT, Asl, Bsl, acc, bm, bn, t);
    const int lane = t & 63, w = t >> 6;
    const int wr = (w >> 1) * 64, wc = (w & 1) * 64;
    const int lr = lane & 15, lk = lane >> 4;
    #pragma unroll
    for (int m = 0; m < 4; m++) {
        int row = bm + wr + m * 16 + lk * 4;
        #pragma unroll
        for (int n = 0; n < 4; n++) {
            int col = bn + wc + n * 16 + lr;
            float bv = bias ? bias[col] : 0.f;
            #pragma unroll
            for (int r = 0; r < 4; r++)
                C[(size_t)(row + r) * G4 + col] = f2b(acc[m][n][r] + bv);
        }
    }
}

// ---------------------------------------------------------------------------
// Fused refine for inst AND phra: out = msg + relu(msg@W1+b1) + relu(feat@W2+b2)
__global__ __launch_bounds__(256) void mfma_refine_kernel(
        const ushort* __restrict__ imsgB, const ushort* __restrict__ instB,
        const ushort* __restrict__ iw1T, const ushort* __restrict__ iw2T,
        const float* __restrict__ ib1, const float* __restrict__ ib2,
        float* __restrict__ iout,
        const ushort* __restrict__ pmsgB, const ushort* __restrict__ phraB,
        const ushort* __restrict__ pw1T, const ushort* __restrict__ pw2T,
        const float* __restrict__ pb1, const float* __restrict__ pb2,
        float* __restrict__ pout) {
    __shared__ ushort Asl[128 * 64];
    __shared__ ushort Bsl[128 * 64];
    const ushort *Am, *Af, *W1, *W2; const float *b1, *b2; float* out;
    int bx = blockIdx.x;
    if (bx < NN / 128) {
        Am = imsgB; Af = instB; W1 = iw1T; W2 = iw2T; b1 = ib1; b2 = ib2; out = iout;
    } else {
        bx -= NN / 128;
        Am = pmsgB; Af = phraB; W1 = pw1T; W2 = pw2T; b1 = pb1; b2 = pb2; out = pout;
    }
    int bm = bx * 128, bn = blockIdx.y * 128;
    int t = threadIdx.x;
    f32x4 acc1[4][4] = {};
    f32x4 acc2[4][4] = {};
    gemm_core(Am, W1, Asl, Bsl, acc1, bm, bn, t);
    gemm_core(Af, W2, Asl, Bsl, acc2, bm, bn, t);
    const int lane = t & 63, w = t >> 6;
    const int wr = (w >> 1) * 64, wc = (w & 1) * 64;
    const int lr = lane & 15, lk = lane >> 4;
    #pragma unroll
    for (int m = 0; m < 4; m++) {
        int row = bm + wr + m * 16 + lk * 4;
        #pragma unroll
        for (int n = 0; n < 4; n++) {
            int col = bn + wc + n * 16 + lr;
            float vb1 = b1[col], vb2 = b2[col];
            #pragma unroll
            for (int r = 0; r < 4; r++) {
                float v = b2f(Am[(size_t)(row + r) * DD + col])
                        + fmaxf(acc1[m][n][r] + vb1, 0.f)
                        + fmaxf(acc2[m][n][r] + vb2, 0.f);
                out[(size_t)(row + r) * DD + col] = v;
            }
        }
    }
}

// ---------------------------------------------------------------------------
// Per-edge gates from bf16 tables (bias pre-folded into Tp). One wave per edge.
__global__ __launch_bounds__(256) void gate_kernel(
        const int* __restrict__ s_idx, const int* __restrict__ o_idx,
        const int* __restrict__ c_idx,
        const ushort* __restrict__ Ti, const ushort* __restrict__ Tp,
        float* __restrict__ gates) {
    int gid = blockIdx.x * 256 + threadIdx.x;
    int e = gid >> 6, lane = gid & 63;
    if (e >= EE) return;
    int s = s_idx[e], o = o_idx[e], c = c_idx[e];
    const unsigned int* tpc = (const unsigned int*)(Tp + (size_t)c * G4);
    const unsigned int* tis = (const unsigned int*)(Ti + (size_t)s * G4);
    const unsigned int* tio = (const unsigned int*)(Ti + (size_t)o * G4);
    auto pairSig = [](unsigned int a, unsigned int b) {
        float lo = __uint_as_float(a << 16) + __uint_as_float(b << 16);
        float hi = __uint_as_float(a & 0xffff0000u) + __uint_as_float(b & 0xffff0000u);
        return sigmoid_relu(lo) + sigmoid_relu(hi);
    };
    float s0 = pairSig(tpc[lane],       tis[lane]);
    float s1 = pairSig(tpc[64 + lane],  tio[64 + lane]);
    float s2 = pairSig(tpc[128 + lane], tio[128 + lane]);
    float s3 = pairSig(tpc[192 + lane], tis[192 + lane]);
    #pragma unroll
    for (int off = 32; off; off >>= 1) {
        s0 += __shfl_xor(s0, off);
        s1 += __shfl_xor(s1, off);
        s2 += __shfl_xor(s2, off);
        s3 += __shfl_xor(s3, off);
    }
    if (lane == 0) {
        const float inv = 1.0f / 128.0f;
        gates[e]          = s0 * inv;
        gates[EE + e]     = s1 * inv;
        gates[2 * EE + e] = s2 * inv;
        gates[3 * EE + e] = s3 * inv;
    }
}

// ---------------------------------------------------------------------------
// Counting sort machinery
__global__ void hist_kernel(const int* __restrict__ s_idx, const int* __restrict__ o_idx,
                            const int* __restrict__ c_idx,
                            int* cntS, int* cntO, int* cntC) {
    int e = blockIdx.x * blockDim.x + threadIdx.x;
    if (e >= EE) return;
    atomicAdd(&cntS[s_idx[e]], 1);
    atomicAdd(&cntO[o_idx[e]], 1);
    atomicAdd(&cntC[c_idx[e]], 1);
}

__global__ __launch_bounds__(1024) void scan3_kernel(
        const int* __restrict__ cntS, const int* __restrict__ cntO,
        const int* __restrict__ cntC,
        int* __restrict__ startS, int* __restrict__ startO, int* __restrict__ startC) {
    const int* cnt; int* start; int n;
    if (blockIdx.x == 0)      { cnt = cntS; start = startS; n = NN; }
    else if (blockIdx.x == 1) { cnt = cntO; start = startO; n = NN; }
    else                      { cnt = cntC; start = startC; n = PP; }
    __shared__ int sh[1024];
    int t = threadIdx.x;
    int per = n >> 10;
    int base = t * per;
    int s = 0;
    for (int i = 0; i < per; i++) s += cnt[base + i];
    sh[t] = s;
    __syncthreads();
    for (int off = 1; off < 1024; off <<= 1) {
        int v = (t >= off) ? sh[t - off] : 0;
        __syncthreads();
        sh[t] += v;
        __syncthreads();
    }
    int ex = (t == 0) ? 0 : sh[t - 1];
    for (int i = 0; i < per; i++) { start[base + i] = ex; ex += cnt[base + i]; }
    if (t == 1023) start[n] = ex;
}

__global__ void scatter_kernel(const int* __restrict__ s_idx, const int* __restrict__ o_idx,
                               const int* __restrict__ c_idx,
                               const int* __restrict__ startS, const int* __restrict__ startO,
                               const int* __restrict__ startC,
                               int* curS, int* curO, int* curC,
                               int* listS, int* listO, int* listC) {
    int e = blockIdx.x * blockDim.x + threadIdx.x;
    if (e >= EE) return;
    int s = s_idx[e];
    listS[startS[s] + atomicAdd(&curS[s], 1)] = e;
    int o = o_idx[e];
    listO[startO[o] + atomicAdd(&curO[o], 1)] = e;
    int c = c_idx[e];
    listC[startC[c] + atomicAdd(&curC[c], 1)] = e;
}

// Pack CSR entries so seg kernels have a 2-load dependent chain.
__global__ __launch_bounds__(256) void packlists_kernel(
        const int* __restrict__ listS, const int* __restrict__ listO,
        const int* __restrict__ listC,
        const int* __restrict__ s_idx, const int* __restrict__ o_idx,
        const int* __restrict__ c_idx, const float* __restrict__ gates,
        int2* __restrict__ pkS, int2* __restrict__ pkO, int4* __restrict__ pkC) {
    int i = blockIdx.x * 256 + threadIdx.x;
    if (i >= EE) return;
    int e = listS[i];
    pkS[i] = make_int2(c_idx[e], __float_as_int(gates[e]));
    e = listO[i];
    pkO[i] = make_int2(c_idx[e], __float_as_int(gates[EE + e]));
    e = listC[i];
    pkC[i] = make_int4(o_idx[e], s_idx[e], __float_as_int(gates[2 * EE + e]),
                       __float_as_int(gates[3 * EE + e]));
}

// ---------------------------------------------------------------------------
__device__ __forceinline__ void accum8(float* acc, uint4 v, float g) {
    acc[0] += g * __uint_as_float(v.x << 16);
    acc[1] += g * __uint_as_float(v.x & 0xffff0000u);
    acc[2] += g * __uint_as_float(v.y << 16);
    acc[3] += g * __uint_as_float(v.y & 0xffff0000u);
    acc[4] += g * __uint_as_float(v.z << 16);
    acc[5] += g * __uint_as_float(v.z & 0xffff0000u);
    acc[6] += g * __uint_as_float(v.w << 16);
    acc[7] += g * __uint_as_float(v.w & 0xffff0000u);
}

// Segment mean, inst side. Block = 4 waves = 2 nodes; per node: S-wave + O-wave.
// Each lane owns 16 dims (dims lane*8..+7 and 512+lane*8..+7). 1-deep prefetch.
__global__ __launch_bounds__(256) void seg_inst_kernel(
        const ushort* __restrict__ phraB,
        const int2* __restrict__ pkS, const int* __restrict__ startS,
        const int2* __restrict__ pkO, const int* __restrict__ startO,
        ushort* __restrict__ msgB) {
    __shared__ float lds[4][64 * 17];
    int w = threadIdx.x >> 6, lane = threadIdx.x & 63;
    int node = blockIdx.x * 2 + (w >> 1);
    const int2* pk_list = (w & 1) ? pkO : pkS;
    const int*  start   = (w & 1) ? startO : startS;
    int b = start[node], e = start[node + 1];
    float acc[16];
    #pragma unroll
    for (int j = 0; j < 16; j++) acc[j] = 0.f;
    if (b < e) {
        int2 pk = pk_list[b];
        const uint4* r = (const uint4*)(phraB + (size_t)pk.x * DD) + lane;
        uint4 c0 = r[0], c1 = r[64];
        for (int i = b + 1; i < e; i++) {
            int2 pkn = pk_list[i];
            const uint4* rn = (const uint4*)(phraB + (size_t)pkn.x * DD) + lane;
            uint4 n0 = rn[0], n1 = rn[64];
            float g = __int_as_float(pk.y);
            accum8(acc, c0, g); accum8(acc + 8, c1, g);
            pk = pkn; c0 = n0; c1 = n1;
        }
        float g = __int_as_float(pk.y);
        accum8(acc, c0, g); accum8(acc + 8, c1, g);
    }
    float scale = 0.5f / (float)max(e - b, 1);
    #pragma unroll
    for (int j = 0; j < 16; j++) lds[w][lane * 17 + j] = acc[j] * scale;
    __syncthreads();
    int u = threadIdx.x & 127;
    int outnode = blockIdx.x * 2 + (threadIdx.x >> 7);
    int w0 = (threadIdx.x >> 7) << 1;
    int off = (u & 63) * 17 + (u >> 6) * 8;
    float4 a0 = *(const float4*)&lds[w0][off];
    float4 a1 = *(const float4*)&lds[w0][off + 4];
    float4 b0 = *(const float4*)&lds[w0 + 1][off];
    float4 b1 = *(const float4*)&lds[w0 + 1][off + 4];
    uint4 o;
    o.x = pack2(a0.x + b0.x, a0.y + b0.y);
    o.y = pack2(a0.z + b0.z, a0.w + b0.w);
    o.z = pack2(a1.x + b1.x, a1.y + b1.y);
    o.w = pack2(a1.z + b1.z, a1.w + b1.w);
    *(uint4*)&msgB[(size_t)outnode * DD + u * 8] = o;
}

// Segment mean, phra side. Block = 4 waves = 2 phrases; 2 waves split a phrase's
// edges (even/odd). Each edge contributes go*inst[o] + gs*inst[s].
__global__ __launch_bounds__(256) void seg_phra_kernel(
        const ushort* __restrict__ instB,
        const int4* __restrict__ pkC, const int* __restrict__ startC,
        ushort* __restrict__ msgB) {
    __shared__ float lds[4][64 * 17];
    int w = threadIdx.x >> 6, lane = threadIdx.x & 63;
    int p = blockIdx.x * 2 + (w >> 1);
    int half = w & 1;
    int cb = startC[p], ce = startC[p + 1];
    float acc[16];
    #pragma unroll
    for (int j = 0; j < 16; j++) acc[j] = 0.f;
    int i0 = cb + half;
    if (i0 < ce) {
        int4 pk = pkC[i0];
        const uint4* ro = (const uint4*)(instB + (size_t)pk.x * DD) + lane;
        const uint4* rs = (const uint4*)(instB + (size_t)pk.y * DD) + lane;
        uint4 o0 = ro[0], o1 = ro[64], s0 = rs[0], s1 = rs[64];
        for (int i = i0 + 2; i < ce; i += 2) {
            int4 pkn = pkC[i];
            const uint4* rno = (const uint4*)(instB + (size_t)pkn.x * DD) + lane;
            const uint4* rns = (const uint4*)(instB + (size_t)pkn.y * DD) + lane;
            uint4 no0 = rno[0], no1 = rno[64], ns0 = rns[0], ns1 = rns[64];
            float go = __int_as_float(pk.z), gs = __int_as_float(pk.w);
            accum8(acc, o0, go); accum8(acc + 8, o1, go);
            accum8(acc, s0, gs); accum8(acc + 8, s1, gs);
            pk = pkn; o0 = no0; o1 = no1; s0 = ns0; s1 = ns1;
        }
        float go = __int_as_float(pk.z), gs = __int_as_float(pk.w);
        accum8(acc, o0, go); accum8(acc + 8, o1, go);
        accum8(acc, s0, gs); accum8(acc + 8, s1, gs);
    }
    float scale = 0.5f / (float)max(ce - cb, 1);
    #pragma unroll
    for (int j = 0; j < 16; j++) lds[w][lane * 17 + j] = acc[j] * scale;
    __syncthreads();
    int u = threadIdx.x & 127;
    int outp = blockIdx.x * 2 + (threadIdx.x >> 7);
    int w0 = (threadIdx.x >> 7) << 1;
    int off = (u & 63) * 17 + (u >> 6) * 8;
    float4 a0 = *(const float4*)&lds[w0][off];
    float4 a1 = *(const float4*)&lds[w0][off + 4];
    float4 b0 = *(const float4*)&lds[w0 + 1][off];
    float4 b1 = *(const float4*)&lds[w0 + 1][off + 4];
    uint4 o;
    o.x = pack2(a0.x + b0.x, a0.y + b0.y);
    o.y = pack2(a0.z + b0.z, a0.w + b0.w);
    o.z = pack2(a1.x + b1.x, a1.y + b1.y);
    o.w = pack2(a1.z + b1.z, a1.w + b1.w);
    *(uint4*)&msgB[(size_t)outp * DD + u * 8] = o;
}

// ---------------------------------------------------------------------------
extern "C" void kernel_launch(void* const* d_in, const int* in_sizes, int n_in,
                              void* d_out, int out_size, void* d_ws, size_t ws_size,
                              hipStream_t stream) {
    (void)in_sizes; (void)n_in; (void)out_size; (void)ws_size;
    const float* inst_feat = (const float*)d_in[0];
    const float* phra_feat = (const float*)d_in[1];
    const int*   conn      = (const int*)d_in[2];
    const int*   clu       = (const int*)d_in[3];
    const float* psW = (const float*)d_in[4];  const float* psB = (const float*)d_in[5];
    const float* poW = (const float*)d_in[6];  const float* poB = (const float*)d_in[7];
    const float* opW = (const float*)d_in[8];  const float* opB = (const float*)d_in[9];
    const float* spW = (const float*)d_in[10]; const float* spB = (const float*)d_in[11];
    const float* iw1W = (const float*)d_in[12]; const float* iw1B = (const float*)d_in[13];
    const float* iw2W = (const float*)d_in[14]; const float* iw2B = (const float*)d_in[15];
    const float* pw1W = (const float*)d_in[16]; const float* pw1B = (const float*)d_in[17];
    const float* pw2W = (const float*)d_in[18]; const float* pw2B = (const float*)d_in[19];
    const int* s_idx = conn;
    const int* o_idx = conn + EE;

    char* ws = (char*)d_ws;
    size_t off = 0;
    auto alloc = [&](size_t bytes) {
        char* p = ws + off;
        off += (bytes + 255) & ~(size_t)255;
        return p;
    };
    ushort* instB = (ushort*)alloc((size_t)NN * DD * 2);
    ushort* phraB = (ushort*)alloc((size_t)PP * DD * 2);
    ushort* WiT   = (ushort*)alloc((size_t)G4 * DD * 2);
    ushort* WpT   = (ushort*)alloc((size_t)G4 * DD * 2);
    ushort* iw1T  = (ushort*)alloc((size_t)DD * DD * 2);
    ushort* iw2T  = (ushort*)alloc((size_t)DD * DD * 2);
    ushort* pw1T  = (ushort*)alloc((size_t)DD * DD * 2);
    ushort* pw2T  = (ushort*)alloc((size_t)DD * DD * 2);
    float* biascat = (float*)alloc(G4 * 4);
    ushort* TiB   = (ushort*)alloc((size_t)NN * G4 * 2);
    ushort* TpB   = (ushort*)alloc((size_t)PP * G4 * 2);
    float* gates  = (float*)alloc((size_t)4 * EE * 4);
    int* cntBlock = (int*)alloc((size_t)(2 * (NN + NN + PP)) * 4);
    int* cntS = cntBlock;      int* cntO = cntS + NN;  int* cntC = cntO + NN;
    int* curS = cntC + PP;     int* curO = curS + NN;  int* curC = curO + NN;
    int* startS = (int*)alloc((NN + 1) * 4);
    int* startO = (int*)alloc((NN + 1) * 4);
    int* startC = (int*)alloc((PP + 1) * 4);
    int* listS  = (int*)alloc((size_t)EE * 4);
    int* listO  = (int*)alloc((size_t)EE * 4);
    int* listC  = (int*)alloc((size_t)EE * 4);
    int2* pkS   = (int2*)alloc((size_t)EE * 8);
    int2* pkO   = (int2*)alloc((size_t)EE * 8);
    int4* pkC   = (int4*)alloc((size_t)EE * 16);
    ushort* imsgB = (ushort*)alloc((size_t)NN * DD * 2);
    ushort* pmsgB = (ushort*)alloc((size_t)PP * DD * 2);

    float* inst_out = (float*)d_out;
    float* phra_out = inst_out + (size_t)NN * DD;

    hipMemsetAsync(cntBlock, 0, (size_t)(2 * (NN + NN + PP)) * 4, stream);

    // Conversions / packing
    f2b2_kernel<<<(NN + PP) * DD / 4 / 256, 256, 0, stream>>>(inst_feat, phra_feat,
                                                              instB, phraB);
    pack_kernel<<<(G4 * DD) / 256, 256, 0, stream>>>(psW, poW, opW, spW, psB, poB, opB, spB,
                                                     WiT, WpT, biascat);
    wtrans4_kernel<<<dim3(DD / 64, DD / 64, 4), 256, 0, stream>>>(
        iw1W, iw2W, pw1W, pw2W, iw1T, iw2T, pw1T, pw2T);

    // CSR build
    hist_kernel<<<EE / 256, 256, 0, stream>>>(s_idx, o_idx, clu, cntS, cntO, cntC);
    scan3_kernel<<<3, 1024, 0, stream>>>(cntS, cntO, cntC, startS, startO, startC);
    scatter_kernel<<<EE / 256, 256, 0, stream>>>(s_idx, o_idx, clu, startS, startO, startC,
                                                 curS, curO, curC, listS, listO, listC);

    // Gate tables (bf16 MFMA, bias folded into Tp)
    mfma_tables_kernel<<<dim3((NN + PP) / 128, G4 / 128), 256, 0, stream>>>(
        instB, WiT, phraB, WpT, biascat, TiB, TpB);

    gate_kernel<<<(EE * 64) / 256, 256, 0, stream>>>(s_idx, o_idx, clu, TiB, TpB, gates);

    packlists_kernel<<<EE / 256, 256, 0, stream>>>(listS, listO, listC, s_idx, o_idx, clu,
                                                   gates, pkS, pkO, pkC);

    // Segment means
    seg_inst_kernel<<<NN / 2, 256, 0, stream>>>(phraB, pkS, startS, pkO, startO, imsgB);
    seg_phra_kernel<<<PP / 2, 256, 0, stream>>>(instB, pkC, startC, pmsgB);

    // Fused refine (both sides in one launch)
    mfma_refine_kernel<<<dim3((NN + PP) / 128, DD / 128), 256, 0, stream>>>(
        imsgB, instB, iw1T, iw2T, iw1B, iw2B, inst_out,
        pmsgB, phraB, pw1T, pw2T, pw1B, pw2B, phra_out);
}

// Round 4
// 193.065 us; speedup vs baseline: 4.6376x; 1.2097x over previous
//
#include <hip/hip_runtime.h>
#include <math.h>

// Problem constants (fixed by the reference)
constexpr int NN  = 4096;   // instances
constexpr int PP  = 2048;   // phrases
constexpr int EE  = 65536;  // edges
constexpr int DD  = 1024;   // feature dim
constexpr int OUTF = 128;   // gate MLP out dim
constexpr int G4  = 512;    // 4 gates * 128

typedef __attribute__((ext_vector_type(8))) short short8v;
typedef __attribute__((ext_vector_type(4))) float f32x4;

__device__ __forceinline__ float sigmoid_relu(float z) {
    z = fmaxf(z, 0.0f);
    return 1.0f / (1.0f + __expf(-z));
}
__device__ __forceinline__ float b2f(ushort u) {
    return __uint_as_float(((unsigned int)u) << 16);
}
__device__ __forceinline__ ushort f2b(float f) {  // RNE
    unsigned int x = __float_as_uint(f);
    return (ushort)((x + 0x7fffu + ((x >> 16) & 1u)) >> 16);
}
__device__ __forceinline__ unsigned int pack2(float a, float b) {
    return (unsigned int)f2b(a) | ((unsigned int)f2b(b) << 16);
}

#define GLD16(gptr, lptr) \
    __builtin_amdgcn_global_load_lds((__attribute__((address_space(1))) const void*)(gptr), \
                                     (__attribute__((address_space(3))) void*)(lptr), 16, 0, 0)

// ---------------------------------------------------------------------------
// f32 -> bf16 for both feature arrays in one launch
__global__ __launch_bounds__(256) void f2b2_kernel(const float* __restrict__ a,
                                                   const float* __restrict__ b,
                                                   ushort* __restrict__ oa,
                                                   ushort* __restrict__ ob) {
    int i = blockIdx.x * 256 + threadIdx.x;
    constexpr int na4 = NN * DD / 4;
    constexpr int nb4 = PP * DD / 4;
    if (i < na4) {
        float4 v = ((const float4*)a)[i];
        ushort4 u; u.x = f2b(v.x); u.y = f2b(v.y); u.z = f2b(v.z); u.w = f2b(v.w);
        ((ushort4*)oa)[i] = u;
    } else if (i - na4 < nb4) {
        int j = i - na4;
        float4 v = ((const float4*)b)[j];
        ushort4 u; u.x = f2b(v.x); u.y = f2b(v.y); u.z = f2b(v.z); u.w = f2b(v.w);
        ((ushort4*)ob)[j] = u;
    }
}

// ---------------------------------------------------------------------------
// Pack gate weights, TRANSPOSED + bf16: WiT/WpT [512][1024]; biascat f32 [512].
__global__ __launch_bounds__(256) void pack_kernel(
        const float* __restrict__ psW, const float* __restrict__ poW,
        const float* __restrict__ opW, const float* __restrict__ spW,
        const float* __restrict__ psB, const float* __restrict__ poB,
        const float* __restrict__ opB, const float* __restrict__ spB,
        ushort* __restrict__ WiT, ushort* __restrict__ WpT,
        float* __restrict__ biascat) {
    int idx = blockIdx.x * 256 + threadIdx.x;
    if (idx >= G4 * DD) return;
    int n = idx >> 10;      // output row (gate-col) 0..511
    int k = idx & 1023;     // input feature 0..1023
    int g = n >> 7, j = n & 127;
    float wi, wp;
    if (g == 0)      { wi = psW[(size_t)(DD + k) * OUTF + j]; wp = psW[(size_t)k * OUTF + j]; }
    else if (g == 1) { wi = poW[(size_t)(DD + k) * OUTF + j]; wp = poW[(size_t)k * OUTF + j]; }
    else if (g == 2) { wi = opW[(size_t)k * OUTF + j];        wp = opW[(size_t)(DD + k) * OUTF + j]; }
    else             { wi = spW[(size_t)k * OUTF + j];        wp = spW[(size_t)(DD + k) * OUTF + j]; }
    WiT[idx] = f2b(wi);
    WpT[idx] = f2b(wp);
    if (idx < G4) {
        int gg = idx >> 7, jj = idx & 127;
        biascat[idx] = (gg == 0) ? psB[jj] : (gg == 1) ? poB[jj] : (gg == 2) ? opB[jj] : spB[jj];
    }
}

// ---------------------------------------------------------------------------
// Transpose-convert all 4 refine weights in one launch (blockIdx.z selects).
__global__ __launch_bounds__(256) void wtrans4_kernel(
        const float* __restrict__ W0, const float* __restrict__ W1,
        const float* __restrict__ W2, const float* __restrict__ W3,
        ushort* __restrict__ T0, ushort* __restrict__ T1,
        ushort* __restrict__ T2, ushort* __restrict__ T3) {
    const float* W; ushort* T;
    switch (blockIdx.z) {
        case 0:  W = W0; T = T0; break;
        case 1:  W = W1; T = T1; break;
        case 2:  W = W2; T = T2; break;
        default: W = W3; T = T3; break;
    }
    __shared__ float tile[64][65];
    int k0 = blockIdx.x * 64, n0 = blockIdx.y * 64;
    int tx = threadIdx.x & 63, ty = threadIdx.x >> 6;  // 64 x 4
    #pragma unroll
    for (int i = 0; i < 64; i += 4)
        tile[ty + i][tx] = W[(size_t)(k0 + ty + i) * DD + n0 + tx];
    __syncthreads();
    #pragma unroll
    for (int i = 0; i < 64; i += 4)
        T[(size_t)(n0 + ty + i) * DD + k0 + tx] = f2b(tile[tx][ty + i]);
}

// ---------------------------------------------------------------------------
// Pipelined MFMA GEMM building blocks. A-tile always 128 rows; B-tile BROWS
// rows (output cols). BK=64, XOR-swizzled linear LDS (rule 21: linear dest +
// inverse-swizzled global source + swizzled ds_read).
template<int BROWS>
__device__ __forceinline__ void stage_tiles(const ushort* __restrict__ A,
                                            const ushort* __restrict__ BT,
                                            int bm, int bn, int k0,
                                            ushort* Asl, ushort* Bsl, int t) {
    #pragma unroll
    for (int r = 0; r < 4; r++) {
        int ch = r * 256 + t;                   // 16B chunk id
        int row = ch >> 3;                      // tile row 0..127
        int sw = ((ch & 7) ^ (row & 7)) << 3;   // pre-swizzled source elem offset
        GLD16(A + (size_t)(bm + row) * DD + k0 + sw, &Asl[ch * 8]);
    }
    #pragma unroll
    for (int r = 0; r < BROWS / 32; r++) {
        int ch = r * 256 + t;
        int row = ch >> 3;
        int sw = ((ch & 7) ^ (row & 7)) << 3;
        GLD16(BT + (size_t)(bn + row) * DD + k0 + sw, &Bsl[ch * 8]);
    }
}

template<int NACC>
__device__ __forceinline__ void compute_tiles(const ushort* Asl, const ushort* Bsl,
                                              f32x4 (&acc)[4][NACC],
                                              int wr, int wc, int lr, int lk) {
    #pragma unroll
    for (int kk = 0; kk < 2; kk++) {
        int ch16 = kk * 4 + lk;
        short8v a[4], b[NACC];
        #pragma unroll
        for (int m = 0; m < 4; m++) {
            int ra = wr + m * 16 + lr;
            a[m] = *(const short8v*)&Asl[ra * 64 + ((ch16 ^ (ra & 7)) << 3)];
        }
        #pragma unroll
        for (int n = 0; n < NACC; n++) {
            int rb = wc + n * 16 + lr;
            b[n] = *(const short8v*)&Bsl[rb * 64 + ((ch16 ^ (rb & 7)) << 3)];
        }
        #pragma unroll
        for (int m = 0; m < 4; m++)
            #pragma unroll
            for (int n = 0; n < NACC; n++)
                acc[m][n] = __builtin_amdgcn_mfma_f32_16x16x32_bf16(a[m], b[n], acc[m][n], 0, 0, 0);
    }
}

// ---------------------------------------------------------------------------
// Gate tables for inst AND phra in one launch. 128x64 tile (grid 48x8 = 384
// blocks, fills all CUs), 2-phase double-buffered pipeline. bf16 out; bias
// folded (phra only).
__global__ __launch_bounds__(256) void mfma_tables_kernel(
        const ushort* __restrict__ instB, const ushort* __restrict__ WiT,
        const ushort* __restrict__ phraB, const ushort* __restrict__ WpT,
        const float* __restrict__ biascat,
        ushort* __restrict__ TiB, ushort* __restrict__ TpB) {
    __shared__ ushort Asl[2][128 * 64];
    __shared__ ushort Bsl[2][64 * 64];
    const ushort *A, *BT; ushort* C; const float* bias;
    int bx = blockIdx.x;
    if (bx < NN / 128) { A = instB; BT = WiT; C = TiB; bias = nullptr; }
    else { bx -= NN / 128; A = phraB; BT = WpT; C = TpB; bias = biascat; }
    int bm = bx * 128, bn = blockIdx.y * 64;
    int t = threadIdx.x;
    const int lane = t & 63, w = t >> 6;
    const int wr = (w >> 1) * 64, wc = (w & 1) * 32;
    const int lr = lane & 15, lk = lane >> 4;
    f32x4 acc[4][2] = {};

    int cur = 0;
    stage_tiles<64>(A, BT, bm, bn, 0, Asl[0], Bsl[0], t);
    __syncthreads();
    for (int k0 = 0; k0 < DD; k0 += 64) {
        int nxt = cur ^ 1;
        if (k0 + 64 < DD)
            stage_tiles<64>(A, BT, bm, bn, k0 + 64, Asl[nxt], Bsl[nxt], t);
        compute_tiles<2>(Asl[cur], Bsl[cur], acc, wr, wc, lr, lk);
        __syncthreads();
        cur = nxt;
    }
    #pragma unroll
    for (int m = 0; m < 4; m++) {
        int row = bm + wr + m * 16 + lk * 4;
        #pragma unroll
        for (int n = 0; n < 2; n++) {
            int col = bn + wc + n * 16 + lr;
            float bv = bias ? bias[col] : 0.f;
            #pragma unroll
            for (int r = 0; r < 4; r++)
                C[(size_t)(row + r) * G4 + col] = f2b(acc[m][n][r] + bv);
        }
    }
}

// ---------------------------------------------------------------------------
// Fused refine for inst AND phra: out = msg + relu(msg@W1+b1) + relu(feat@W2+b2)
// Single continuous 32-step (virtual K=2048) double-buffered pipeline.
__global__ __launch_bounds__(256) void mfma_refine_kernel(
        const ushort* __restrict__ imsgB, const ushort* __restrict__ instB,
        const ushort* __restrict__ iw1T, const ushort* __restrict__ iw2T,
        const float* __restrict__ ib1, const float* __restrict__ ib2,
        float* __restrict__ iout,
        const ushort* __restrict__ pmsgB, const ushort* __restrict__ phraB,
        const ushort* __restrict__ pw1T, const ushort* __restrict__ pw2T,
        const float* __restrict__ pb1, const float* __restrict__ pb2,
        float* __restrict__ pout) {
    __shared__ ushort Asl[2][128 * 64];
    __shared__ ushort Bsl[2][128 * 64];
    const ushort *Am, *Af, *W1, *W2; const float *b1, *b2; float* out;
    int bx = blockIdx.x;
    if (bx < NN / 128) {
        Am = imsgB; Af = instB; W1 = iw1T; W2 = iw2T; b1 = ib1; b2 = ib2; out = iout;
    } else {
        bx -= NN / 128;
        Am = pmsgB; Af = phraB; W1 = pw1T; W2 = pw2T; b1 = pb1; b2 = pb2; out = pout;
    }
    int bm = bx * 128, bn = blockIdx.y * 128;
    int t = threadIdx.x;
    const int lane = t & 63, w = t >> 6;
    const int wr = (w >> 1) * 64, wc = (w & 1) * 64;
    const int lr = lane & 15, lk = lane >> 4;
    f32x4 acc1[4][4] = {};
    f32x4 acc2[4][4] = {};

    int cur = 0;
    stage_tiles<128>(Am, W1, bm, bn, 0, Asl[0], Bsl[0], t);
    __syncthreads();
    auto run = [&](const ushort* A, const ushort* B, f32x4 (&acc)[4][4],
                   const ushort* An, const ushort* Bn) {
        for (int k0 = 0; k0 < DD; k0 += 64) {
            int nxt = cur ^ 1;
            if (k0 + 64 < DD)
                stage_tiles<128>(A, B, bm, bn, k0 + 64, Asl[nxt], Bsl[nxt], t);
            else if (An)
                stage_tiles<128>(An, Bn, bm, bn, 0, Asl[nxt], Bsl[nxt], t);
            compute_tiles<4>(Asl[cur], Bsl[cur], acc, wr, wc, lr, lk);
            __syncthreads();
            cur = nxt;
        }
    };
    run(Am, W1, acc1, Af, W2);
    run(Af, W2, acc2, nullptr, nullptr);

    #pragma unroll
    for (int m = 0; m < 4; m++) {
        int row = bm + wr + m * 16 + lk * 4;
        #pragma unroll
        for (int n = 0; n < 4; n++) {
            int col = bn + wc + n * 16 + lr;
            float vb1 = b1[col], vb2 = b2[col];
            #pragma unroll
            for (int r = 0; r < 4; r++) {
                float v = b2f(Am[(size_t)(row + r) * DD + col])
                        + fmaxf(acc1[m][n][r] + vb1, 0.f)
                        + fmaxf(acc2[m][n][r] + vb2, 0.f);
                out[(size_t)(row + r) * DD + col] = v;
            }
        }
    }
}

// ---------------------------------------------------------------------------
// Per-edge gates from bf16 tables (bias pre-folded into Tp). One wave per edge.
__global__ __launch_bounds__(256) void gate_kernel(
        const int* __restrict__ s_idx, const int* __restrict__ o_idx,
        const int* __restrict__ c_idx,
        const ushort* __restrict__ Ti, const ushort* __restrict__ Tp,
        float* __restrict__ gates) {
    int gid = blockIdx.x * 256 + threadIdx.x;
    int e = gid >> 6, lane = gid & 63;
    if (e >= EE) return;
    int s = s_idx[e], o = o_idx[e], c = c_idx[e];
    const unsigned int* tpc = (const unsigned int*)(Tp + (size_t)c * G4);
    const unsigned int* tis = (const unsigned int*)(Ti + (size_t)s * G4);
    const unsigned int* tio = (const unsigned int*)(Ti + (size_t)o * G4);
    auto pairSig = [](unsigned int a, unsigned int b) {
        float lo = __uint_as_float(a << 16) + __uint_as_float(b << 16);
        float hi = __uint_as_float(a & 0xffff0000u) + __uint_as_float(b & 0xffff0000u);
        return sigmoid_relu(lo) + sigmoid_relu(hi);
    };
    float s0 = pairSig(tpc[lane],       tis[lane]);
    float s1 = pairSig(tpc[64 + lane],  tio[64 + lane]);
    float s2 = pairSig(tpc[128 + lane], tio[128 + lane]);
    float s3 = pairSig(tpc[192 + lane], tis[192 + lane]);
    #pragma unroll
    for (int off = 32; off; off >>= 1) {
        s0 += __shfl_xor(s0, off);
        s1 += __shfl_xor(s1, off);
        s2 += __shfl_xor(s2, off);
        s3 += __shfl_xor(s3, off);
    }
    if (lane == 0) {
        const float inv = 1.0f / 128.0f;
        gates[e]          = s0 * inv;
        gates[EE + e]     = s1 * inv;
        gates[2 * EE + e] = s2 * inv;
        gates[3 * EE + e] = s3 * inv;
    }
}

// ---------------------------------------------------------------------------
// Counting sort machinery
__global__ void hist_kernel(const int* __restrict__ s_idx, const int* __restrict__ o_idx,
                            const int* __restrict__ c_idx,
                            int* cntS, int* cntO, int* cntC) {
    int e = blockIdx.x * blockDim.x + threadIdx.x;
    if (e >= EE) return;
    atomicAdd(&cntS[s_idx[e]], 1);
    atomicAdd(&cntO[o_idx[e]], 1);
    atomicAdd(&cntC[c_idx[e]], 1);
}

__global__ __launch_bounds__(1024) void scan3_kernel(
        const int* __restrict__ cntS, const int* __restrict__ cntO,
        const int* __restrict__ cntC,
        int* __restrict__ startS, int* __restrict__ startO, int* __restrict__ startC) {
    const int* cnt; int* start; int n;
    if (blockIdx.x == 0)      { cnt = cntS; start = startS; n = NN; }
    else if (blockIdx.x == 1) { cnt = cntO; start = startO; n = NN; }
    else                      { cnt = cntC; start = startC; n = PP; }
    __shared__ int sh[1024];
    int t = threadIdx.x;
    int per = n >> 10;
    int base = t * per;
    int s = 0;
    for (int i = 0; i < per; i++) s += cnt[base + i];
    sh[t] = s;
    __syncthreads();
    for (int off = 1; off < 1024; off <<= 1) {
        int v = (t >= off) ? sh[t - off] : 0;
        __syncthreads();
        sh[t] += v;
        __syncthreads();
    }
    int ex = (t == 0) ? 0 : sh[t - 1];
    for (int i = 0; i < per; i++) { start[base + i] = ex; ex += cnt[base + i]; }
    if (t == 1023) start[n] = ex;
}

__global__ void scatter_kernel(const int* __restrict__ s_idx, const int* __restrict__ o_idx,
                               const int* __restrict__ c_idx,
                               const int* __restrict__ startS, const int* __restrict__ startO,
                               const int* __restrict__ startC,
                               int* curS, int* curO, int* curC,
                               int* listS, int* listO, int* listC) {
    int e = blockIdx.x * blockDim.x + threadIdx.x;
    if (e >= EE) return;
    int s = s_idx[e];
    listS[startS[s] + atomicAdd(&curS[s], 1)] = e;
    int o = o_idx[e];
    listO[startO[o] + atomicAdd(&curO[o], 1)] = e;
    int c = c_idx[e];
    listC[startC[c] + atomicAdd(&curC[c], 1)] = e;
}

// Pack CSR entries so seg kernels have a 2-load dependent chain.
__global__ __launch_bounds__(256) void packlists_kernel(
        const int* __restrict__ listS, const int* __restrict__ listO,
        const int* __restrict__ listC,
        const int* __restrict__ s_idx, const int* __restrict__ o_idx,
        const int* __restrict__ c_idx, const float* __restrict__ gates,
        int2* __restrict__ pkS, int2* __restrict__ pkO, int4* __restrict__ pkC) {
    int i = blockIdx.x * 256 + threadIdx.x;
    if (i >= EE) return;
    int e = listS[i];
    pkS[i] = make_int2(c_idx[e], __float_as_int(gates[e]));
    e = listO[i];
    pkO[i] = make_int2(c_idx[e], __float_as_int(gates[EE + e]));
    e = listC[i];
    pkC[i] = make_int4(o_idx[e], s_idx[e], __float_as_int(gates[2 * EE + e]),
                       __float_as_int(gates[3 * EE + e]));
}

// ---------------------------------------------------------------------------
__device__ __forceinline__ void accum8(float* acc, uint4 v, float g) {
    acc[0] += g * __uint_as_float(v.x << 16);
    acc[1] += g * __uint_as_float(v.x & 0xffff0000u);
    acc[2] += g * __uint_as_float(v.y << 16);
    acc[3] += g * __uint_as_float(v.y & 0xffff0000u);
    acc[4] += g * __uint_as_float(v.z << 16);
    acc[5] += g * __uint_as_float(v.z & 0xffff0000u);
    acc[6] += g * __uint_as_float(v.w << 16);
    acc[7] += g * __uint_as_float(v.w & 0xffff0000u);
}

// Segment mean, inst side. Block = 4 waves = 2 nodes; per node: S-wave + O-wave.
__global__ __launch_bounds__(256) void seg_inst_kernel(
        const ushort* __restrict__ phraB,
        const int2* __restrict__ pkS, const int* __restrict__ startS,
        const int2* __restrict__ pkO, const int* __restrict__ startO,
        ushort* __restrict__ msgB) {
    __shared__ float lds[4][64 * 17];
    int w = threadIdx.x >> 6, lane = threadIdx.x & 63;
    int node = blockIdx.x * 2 + (w >> 1);
    const int2* pk_list = (w & 1) ? pkO : pkS;
    const int*  start   = (w & 1) ? startO : startS;
    int b = start[node], e = start[node + 1];
    float acc[16];
    #pragma unroll
    for (int j = 0; j < 16; j++) acc[j] = 0.f;
    if (b < e) {
        int2 pk = pk_list[b];
        const uint4* r = (const uint4*)(phraB + (size_t)pk.x * DD) + lane;
        uint4 c0 = r[0], c1 = r[64];
        for (int i = b + 1; i < e; i++) {
            int2 pkn = pk_list[i];
            const uint4* rn = (const uint4*)(phraB + (size_t)pkn.x * DD) + lane;
            uint4 n0 = rn[0], n1 = rn[64];
            float g = __int_as_float(pk.y);
            accum8(acc, c0, g); accum8(acc + 8, c1, g);
            pk = pkn; c0 = n0; c1 = n1;
        }
        float g = __int_as_float(pk.y);
        accum8(acc, c0, g); accum8(acc + 8, c1, g);
    }
    float scale = 0.5f / (float)max(e - b, 1);
    #pragma unroll
    for (int j = 0; j < 16; j++) lds[w][lane * 17 + j] = acc[j] * scale;
    __syncthreads();
    int u = threadIdx.x & 127;
    int outnode = blockIdx.x * 2 + (threadIdx.x >> 7);
    int w0 = (threadIdx.x >> 7) << 1;
    int off = (u & 63) * 17 + (u >> 6) * 8;
    float4 a0 = *(const float4*)&lds[w0][off];
    float4 a1 = *(const float4*)&lds[w0][off + 4];
    float4 b0 = *(const float4*)&lds[w0 + 1][off];
    float4 b1 = *(const float4*)&lds[w0 + 1][off + 4];
    uint4 o;
    o.x = pack2(a0.x + b0.x, a0.y + b0.y);
    o.y = pack2(a0.z + b0.z, a0.w + b0.w);
    o.z = pack2(a1.x + b1.x, a1.y + b1.y);
    o.w = pack2(a1.z + b1.z, a1.w + b1.w);
    *(uint4*)&msgB[(size_t)outnode * DD + u * 8] = o;
}

// Segment mean, phra side. Block = 4 waves = 2 phrases; 2 waves split edges.
__global__ __launch_bounds__(256) void seg_phra_kernel(
        const ushort* __restrict__ instB,
        const int4* __restrict__ pkC, const int* __restrict__ startC,
        ushort* __restrict__ msgB) {
    __shared__ float lds[4][64 * 17];
    int w = threadIdx.x >> 6, lane = threadIdx.x & 63;
    int p = blockIdx.x * 2 + (w >> 1);
    int half = w & 1;
    int cb = startC[p], ce = startC[p + 1];
    float acc[16];
    #pragma unroll
    for (int j = 0; j < 16; j++) acc[j] = 0.f;
    int i0 = cb + half;
    if (i0 < ce) {
        int4 pk = pkC[i0];
        const uint4* ro = (const uint4*)(instB + (size_t)pk.x * DD) + lane;
        const uint4* rs = (const uint4*)(instB + (size_t)pk.y * DD) + lane;
        uint4 o0 = ro[0], o1 = ro[64], s0 = rs[0], s1 = rs[64];
        for (int i = i0 + 2; i < ce; i += 2) {
            int4 pkn = pkC[i];
            const uint4* rno = (const uint4*)(instB + (size_t)pkn.x * DD) + lane;
            const uint4* rns = (const uint4*)(instB + (size_t)pkn.y * DD) + lane;
            uint4 no0 = rno[0], no1 = rno[64], ns0 = rns[0], ns1 = rns[64];
            float go = __int_as_float(pk.z), gs = __int_as_float(pk.w);
            accum8(acc, o0, go); accum8(acc + 8, o1, go);
            accum8(acc, s0, gs); accum8(acc + 8, s1, gs);
            pk = pkn; o0 = no0; o1 = no1; s0 = ns0; s1 = ns1;
        }
        float go = __int_as_float(pk.z), gs = __int_as_float(pk.w);
        accum8(acc, o0, go); accum8(acc + 8, o1, go);
        accum8(acc, s0, gs); accum8(acc + 8, s1, gs);
    }
    float scale = 0.5f / (float)max(ce - cb, 1);
    #pragma unroll
    for (int j = 0; j < 16; j++) lds[w][lane * 17 + j] = acc[j] * scale;
    __syncthreads();
    int u = threadIdx.x & 127;
    int outp = blockIdx.x * 2 + (threadIdx.x >> 7);
    int w0 = (threadIdx.x >> 7) << 1;
    int off = (u & 63) * 17 + (u >> 6) * 8;
    float4 a0 = *(const float4*)&lds[w0][off];
    float4 a1 = *(const float4*)&lds[w0][off + 4];
    float4 b0 = *(const float4*)&lds[w0 + 1][off];
    float4 b1 = *(const float4*)&lds[w0 + 1][off + 4];
    uint4 o;
    o.x = pack2(a0.x + b0.x, a0.y + b0.y);
    o.y = pack2(a0.z + b0.z, a0.w + b0.w);
    o.z = pack2(a1.x + b1.x, a1.y + b1.y);
    o.w = pack2(a1.z + b1.z, a1.w + b1.w);
    *(uint4*)&msgB[(size_t)outp * DD + u * 8] = o;
}

// ---------------------------------------------------------------------------
extern "C" void kernel_launch(void* const* d_in, const int* in_sizes, int n_in,
                              void* d_out, int out_size, void* d_ws, size_t ws_size,
                              hipStream_t stream) {
    (void)in_sizes; (void)n_in; (void)out_size; (void)ws_size;
    const float* inst_feat = (const float*)d_in[0];
    const float* phra_feat = (const float*)d_in[1];
    const int*   conn      = (const int*)d_in[2];
    const int*   clu       = (const int*)d_in[3];
    const float* psW = (const float*)d_in[4];  const float* psB = (const float*)d_in[5];
    const float* poW = (const float*)d_in[6];  const float* poB = (const float*)d_in[7];
    const float* opW = (const float*)d_in[8];  const float* opB = (const float*)d_in[9];
    const float* spW = (const float*)d_in[10]; const float* spB = (const float*)d_in[11];
    const float* iw1W = (const float*)d_in[12]; const float* iw1B = (const float*)d_in[13];
    const float* iw2W = (const float*)d_in[14]; const float* iw2B = (const float*)d_in[15];
    const float* pw1W = (const float*)d_in[16]; const float* pw1B = (const float*)d_in[17];
    const float* pw2W = (const float*)d_in[18]; const float* pw2B = (const float*)d_in[19];
    const int* s_idx = conn;
    const int* o_idx = conn + EE;

    char* ws = (char*)d_ws;
    size_t off = 0;
    auto alloc = [&](size_t bytes) {
        char* p = ws + off;
        off += (bytes + 255) & ~(size_t)255;
        return p;
    };
    ushort* instB = (ushort*)alloc((size_t)NN * DD * 2);
    ushort* phraB = (ushort*)alloc((size_t)PP * DD * 2);
    ushort* WiT   = (ushort*)alloc((size_t)G4 * DD * 2);
    ushort* WpT   = (ushort*)alloc((size_t)G4 * DD * 2);
    ushort* iw1T  = (ushort*)alloc((size_t)DD * DD * 2);
    ushort* iw2T  = (ushort*)alloc((size_t)DD * DD * 2);
    ushort* pw1T  = (ushort*)alloc((size_t)DD * DD * 2);
    ushort* pw2T  = (ushort*)alloc((size_t)DD * DD * 2);
    float* biascat = (float*)alloc(G4 * 4);
    ushort* TiB   = (ushort*)alloc((size_t)NN * G4 * 2);
    ushort* TpB   = (ushort*)alloc((size_t)PP * G4 * 2);
    float* gates  = (float*)alloc((size_t)4 * EE * 4);
    int* cntBlock = (int*)alloc((size_t)(2 * (NN + NN + PP)) * 4);
    int* cntS = cntBlock;      int* cntO = cntS + NN;  int* cntC = cntO + NN;
    int* curS = cntC + PP;     int* curO = curS + NN;  int* curC = curO + NN;
    int* startS = (int*)alloc((NN + 1) * 4);
    int* startO = (int*)alloc((NN + 1) * 4);
    int* startC = (int*)alloc((PP + 1) * 4);
    int* listS  = (int*)alloc((size_t)EE * 4);
    int* listO  = (int*)alloc((size_t)EE * 4);
    int* listC  = (int*)alloc((size_t)EE * 4);
    int2* pkS   = (int2*)alloc((size_t)EE * 8);
    int2* pkO   = (int2*)alloc((size_t)EE * 8);
    int4* pkC   = (int4*)alloc((size_t)EE * 16);
    ushort* imsgB = (ushort*)alloc((size_t)NN * DD * 2);
    ushort* pmsgB = (ushort*)alloc((size_t)PP * DD * 2);

    float* inst_out = (float*)d_out;
    float* phra_out = inst_out + (size_t)NN * DD;

    hipMemsetAsync(cntBlock, 0, (size_t)(2 * (NN + NN + PP)) * 4, stream);

    // Conversions / packing
    f2b2_kernel<<<(NN + PP) * DD / 4 / 256, 256, 0, stream>>>(inst_feat, phra_feat,
                                                              instB, phraB);
    pack_kernel<<<(G4 * DD) / 256, 256, 0, stream>>>(psW, poW, opW, spW, psB, poB, opB, spB,
                                                     WiT, WpT, biascat);
    wtrans4_kernel<<<dim3(DD / 64, DD / 64, 4), 256, 0, stream>>>(
        iw1W, iw2W, pw1W, pw2W, iw1T, iw2T, pw1T, pw2T);

    // CSR build
    hist_kernel<<<EE / 256, 256, 0, stream>>>(s_idx, o_idx, clu, cntS, cntO, cntC);
    scan3_kernel<<<3, 1024, 0, stream>>>(cntS, cntO, cntC, startS, startO, startC);
    scatter_kernel<<<EE / 256, 256, 0, stream>>>(s_idx, o_idx, clu, startS, startO, startC,
                                                 curS, curO, curC, listS, listO, listC);

    // Gate tables (bf16 MFMA, bias folded into Tp)
    mfma_tables_kernel<<<dim3((NN + PP) / 128, G4 / 64), 256, 0, stream>>>(
        instB, WiT, phraB, WpT, biascat, TiB, TpB);

    gate_kernel<<<(EE * 64) / 256, 256, 0, stream>>>(s_idx, o_idx, clu, TiB, TpB, gates);

    packlists_kernel<<<EE / 256, 256, 0, stream>>>(listS, listO, listC, s_idx, o_idx, clu,
                                                   gates, pkS, pkO, pkC);

    // Segment means
    seg_inst_kernel<<<NN / 2, 256, 0, stream>>>(phraB, pkS, startS, pkO, startO, imsgB);
    seg_phra_kernel<<<PP / 2, 256, 0, stream>>>(instB, pkC, startC, pmsgB);

    // Fused refine (both sides, continuous pipeline)
    mfma_refine_kernel<<<dim3((NN + PP) / 128, DD / 128), 256, 0, stream>>>(
        imsgB, instB, iw1T, iw2T, iw1B, iw2B, inst_out,
        pmsgB, phraB, pw1T, pw2T, pw1B, pw2B, phra_out);
}

// Round 5
// 186.017 us; speedup vs baseline: 4.8133x; 1.0379x over previous
//
#include <hip/hip_runtime.h>
#include <math.h>

// Problem constants (fixed by the reference)
constexpr int NN  = 4096;   // instances
constexpr int PP  = 2048;   // phrases
constexpr int EE  = 65536;  // edges
constexpr int DD  = 1024;   // feature dim
constexpr int OUTF = 128;   // gate MLP out dim
constexpr int G4  = 512;    // 4 gates * 128

typedef __attribute__((ext_vector_type(8))) short short8v;
typedef __attribute__((ext_vector_type(4))) float f32x4;

__device__ __forceinline__ float sigmoid_relu(float z) {
    z = fmaxf(z, 0.0f);
    return 1.0f / (1.0f + __expf(-z));
}
__device__ __forceinline__ float b2f(ushort u) {
    return __uint_as_float(((unsigned int)u) << 16);
}
__device__ __forceinline__ ushort f2b(float f) {  // RNE
    unsigned int x = __float_as_uint(f);
    return (ushort)((x + 0x7fffu + ((x >> 16) & 1u)) >> 16);
}
__device__ __forceinline__ unsigned int pack2(float a, float b) {
    return (unsigned int)f2b(a) | ((unsigned int)f2b(b) << 16);
}

#define GLD16(gptr, lptr) \
    __builtin_amdgcn_global_load_lds((__attribute__((address_space(1))) const void*)(gptr), \
                                     (__attribute__((address_space(3))) void*)(lptr), 16, 0, 0)
// Counted-vmcnt pipeline primitives (T4): keep just-issued loads in flight.
#define ASM_VMCNT(n) asm volatile("s_waitcnt vmcnt(" #n ")" ::: "memory")
#define BARRIER() do { asm volatile("" ::: "memory"); \
                       __builtin_amdgcn_s_barrier();  \
                       asm volatile("" ::: "memory"); } while (0)

// ---------------------------------------------------------------------------
// Fused prep: f32->bf16 features, gate-weight pack, refine-weight transpose.
constexpr int NB_F2B  = (NN + PP) * DD / 4 / 256;  // 6144
constexpr int NB_PACK = G4 * DD / 256;             // 2048
constexpr int NB_WT   = 4 * (DD / 64) * (DD / 64); // 1024

__global__ __launch_bounds__(256) void prep_kernel(
        const float* __restrict__ instF, const float* __restrict__ phraF,
        ushort* __restrict__ instB, ushort* __restrict__ phraB,
        const float* __restrict__ psW, const float* __restrict__ poW,
        const float* __restrict__ opW, const float* __restrict__ spW,
        const float* __restrict__ psB, const float* __restrict__ poB,
        const float* __restrict__ opB, const float* __restrict__ spB,
        ushort* __restrict__ WiT, ushort* __restrict__ WpT,
        float* __restrict__ biascat,
        const float* __restrict__ W0, const float* __restrict__ W1,
        const float* __restrict__ W2, const float* __restrict__ W3,
        ushort* __restrict__ T0, ushort* __restrict__ T1,
        ushort* __restrict__ T2, ushort* __restrict__ T3) {
    __shared__ float tile[64][65];
    int b = blockIdx.x, t = threadIdx.x;
    if (b < NB_F2B) {
        int i = b * 256 + t;
        constexpr int na4 = NN * DD / 4;
        if (i < na4) {
            float4 v = ((const float4*)instF)[i];
            ushort4 u; u.x = f2b(v.x); u.y = f2b(v.y); u.z = f2b(v.z); u.w = f2b(v.w);
            ((ushort4*)instB)[i] = u;
        } else {
            int j = i - na4;
            float4 v = ((const float4*)phraF)[j];
            ushort4 u; u.x = f2b(v.x); u.y = f2b(v.y); u.z = f2b(v.z); u.w = f2b(v.w);
            ((ushort4*)phraB)[j] = u;
        }
        return;
    }
    b -= NB_F2B;
    if (b < NB_PACK) {
        int idx = b * 256 + t;
        int n = idx >> 10, k = idx & 1023;
        int g = n >> 7, j = n & 127;
        float wi, wp;
        if (g == 0)      { wi = psW[(size_t)(DD + k) * OUTF + j]; wp = psW[(size_t)k * OUTF + j]; }
        else if (g == 1) { wi = poW[(size_t)(DD + k) * OUTF + j]; wp = poW[(size_t)k * OUTF + j]; }
        else if (g == 2) { wi = opW[(size_t)k * OUTF + j];        wp = opW[(size_t)(DD + k) * OUTF + j]; }
        else             { wi = spW[(size_t)k * OUTF + j];        wp = spW[(size_t)(DD + k) * OUTF + j]; }
        WiT[idx] = f2b(wi);
        WpT[idx] = f2b(wp);
        if (idx < G4) {
            int gg = idx >> 7, jj = idx & 127;
            biascat[idx] = (gg == 0) ? psB[jj] : (gg == 1) ? poB[jj]
                         : (gg == 2) ? opB[jj] : spB[jj];
        }
        return;
    }
    b -= NB_PACK;
    int z = b >> 8, rest = b & 255;
    const float* W = (z == 0) ? W0 : (z == 1) ? W1 : (z == 2) ? W2 : W3;
    ushort*      T = (z == 0) ? T0 : (z == 1) ? T1 : (z == 2) ? T2 : T3;
    int k0 = (rest & 15) * 64, n0 = (rest >> 4) * 64;
    int tx = t & 63, ty = t >> 6;
    #pragma unroll
    for (int i = 0; i < 64; i += 4)
        tile[ty + i][tx] = W[(size_t)(k0 + ty + i) * DD + n0 + tx];
    __syncthreads();
    #pragma unroll
    for (int i = 0; i < 64; i += 4)
        T[(size_t)(n0 + ty + i) * DD + k0 + tx] = f2b(tile[tx][ty + i]);
}

// ---------------------------------------------------------------------------
// Pipelined MFMA GEMM building blocks. A-tile 128 rows; B-tile BROWS rows.
// BK=64, XOR-swizzled linear LDS (rule 21).
template<int BROWS>
__device__ __forceinline__ void stage_tiles(const ushort* __restrict__ A,
                                            const ushort* __restrict__ BT,
                                            int bm, int bn, int k0,
                                            ushort* Asl, ushort* Bsl, int t) {
    #pragma unroll
    for (int r = 0; r < 4; r++) {
        int ch = r * 256 + t;
        int row = ch >> 3;
        int sw = ((ch & 7) ^ (row & 7)) << 3;
        GLD16(A + (size_t)(bm + row) * DD + k0 + sw, &Asl[ch * 8]);
    }
    #pragma unroll
    for (int r = 0; r < BROWS / 32; r++) {
        int ch = r * 256 + t;
        int row = ch >> 3;
        int sw = ((ch & 7) ^ (row & 7)) << 3;
        GLD16(BT + (size_t)(bn + row) * DD + k0 + sw, &Bsl[ch * 8]);
    }
}

template<int NACC>
__device__ __forceinline__ void compute_tiles(const ushort* Asl, const ushort* Bsl,
                                              f32x4 (&acc)[4][NACC],
                                              int wr, int wc, int lr, int lk) {
    #pragma unroll
    for (int kk = 0; kk < 2; kk++) {
        int ch16 = kk * 4 + lk;
        short8v a[4], b[NACC];
        #pragma unroll
        for (int m = 0; m < 4; m++) {
            int ra = wr + m * 16 + lr;
            a[m] = *(const short8v*)&Asl[ra * 64 + ((ch16 ^ (ra & 7)) << 3)];
        }
        #pragma unroll
        for (int n = 0; n < NACC; n++) {
            int rb = wc + n * 16 + lr;
            b[n] = *(const short8v*)&Bsl[rb * 64 + ((ch16 ^ (rb & 7)) << 3)];
        }
        #pragma unroll
        for (int m = 0; m < 4; m++)
            #pragma unroll
            for (int n = 0; n < NACC; n++)
                acc[m][n] = __builtin_amdgcn_mfma_f32_16x16x32_bf16(a[m], b[n], acc[m][n], 0, 0, 0);
    }
}

// ---------------------------------------------------------------------------
// Gate tables, 128x64 tile, counted-vmcnt 2-buffer pipeline, XCD panel swizzle.
__global__ __launch_bounds__(256) void mfma_tables_kernel(
        const ushort* __restrict__ instB, const ushort* __restrict__ WiT,
        const ushort* __restrict__ phraB, const ushort* __restrict__ WpT,
        const float* __restrict__ biascat,
        ushort* __restrict__ TiB, ushort* __restrict__ TpB) {
    __shared__ ushort Asl[2][128 * 64];
    __shared__ ushort Bsl[2][64 * 64];
    // grid is (48, 8); remap so lin&7 selects the B-panel -> one panel per XCD
    int lin = blockIdx.y * gridDim.x + blockIdx.x;
    int by = lin & 7;
    int bx = lin >> 3;
    const ushort *A, *BT; ushort* C; const float* bias;
    if (bx < NN / 128) { A = instB; BT = WiT; C = TiB; bias = nullptr; }
    else { bx -= NN / 128; A = phraB; BT = WpT; C = TpB; bias = biascat; }
    int bm = bx * 128, bn = by * 64;
    int t = threadIdx.x;
    const int lane = t & 63, w = t >> 6;
    const int wr = (w >> 1) * 64, wc = (w & 1) * 32;
    const int lr = lane & 15, lk = lane >> 4;
    f32x4 acc[4][2] = {};

    int cur = 0;
    stage_tiles<64>(A, BT, bm, bn, 0, Asl[0], Bsl[0], t);
    for (int k0 = 0; k0 < DD; k0 += 64) {
        int nxt = cur ^ 1;
        if (k0 + 64 < DD) {
            stage_tiles<64>(A, BT, bm, bn, k0 + 64, Asl[nxt], Bsl[nxt], t);
            ASM_VMCNT(6);
        } else {
            ASM_VMCNT(0);
        }
        BARRIER();
        compute_tiles<2>(Asl[cur], Bsl[cur], acc, wr, wc, lr, lk);
        BARRIER();
        cur = nxt;
    }
    #pragma unroll
    for (int m = 0; m < 4; m++) {
        int row = bm + wr + m * 16 + lk * 4;
        #pragma unroll
        for (int n = 0; n < 2; n++) {
            int col = bn + wc + n * 16 + lr;
            float bv = bias ? bias[col] : 0.f;
            #pragma unroll
            for (int r = 0; r < 4; r++)
                C[(size_t)(row + r) * G4 + col] = f2b(acc[m][n][r] + bv);
        }
    }
}

// ---------------------------------------------------------------------------
// Fused refine: out = msg + relu(msg@W1+b1) + relu(feat@W2+b2).
// Continuous 32-step counted-vmcnt pipeline, XCD panel swizzle.
__global__ __launch_bounds__(256) void mfma_refine_kernel(
        const ushort* __restrict__ imsgB, const ushort* __restrict__ instB,
        const ushort* __restrict__ iw1T, const ushort* __restrict__ iw2T,
        const float* __restrict__ ib1, const float* __restrict__ ib2,
        float* __restrict__ iout,
        const ushort* __restrict__ pmsgB, const ushort* __restrict__ phraB,
        const ushort* __restrict__ pw1T, const ushort* __restrict__ pw2T,
        const float* __restrict__ pb1, const float* __restrict__ pb2,
        float* __restrict__ pout) {
    __shared__ ushort Asl[2][128 * 64];
    __shared__ ushort Bsl[2][128 * 64];
    int lin = blockIdx.y * gridDim.x + blockIdx.x;
    int by = lin & 7;
    int bx = lin >> 3;
    const ushort *Am, *Af, *W1, *W2; const float *b1, *b2; float* out;
    if (bx < NN / 128) {
        Am = imsgB; Af = instB; W1 = iw1T; W2 = iw2T; b1 = ib1; b2 = ib2; out = iout;
    } else {
        bx -= NN / 128;
        Am = pmsgB; Af = phraB; W1 = pw1T; W2 = pw2T; b1 = pb1; b2 = pb2; out = pout;
    }
    int bm = bx * 128, bn = by * 128;
    int t = threadIdx.x;
    const int lane = t & 63, w = t >> 6;
    const int wr = (w >> 1) * 64, wc = (w & 1) * 64;
    const int lr = lane & 15, lk = lane >> 4;
    f32x4 acc1[4][4] = {};
    f32x4 acc2[4][4] = {};

    int cur = 0;
    stage_tiles<128>(Am, W1, bm, bn, 0, Asl[0], Bsl[0], t);
    auto run = [&](const ushort* A, const ushort* B, f32x4 (&acc)[4][4],
                   const ushort* An, const ushort* Bn) {
        for (int k0 = 0; k0 < DD; k0 += 64) {
            int nxt = cur ^ 1;
            if (k0 + 64 < DD) {
                stage_tiles<128>(A, B, bm, bn, k0 + 64, Asl[nxt], Bsl[nxt], t);
                ASM_VMCNT(8);
            } else if (An) {
                stage_tiles<128>(An, Bn, bm, bn, 0, Asl[nxt], Bsl[nxt], t);
                ASM_VMCNT(8);
            } else {
                ASM_VMCNT(0);
            }
            BARRIER();
            compute_tiles<4>(Asl[cur], Bsl[cur], acc, wr, wc, lr, lk);
            BARRIER();
            cur = nxt;
        }
    };
    run(Am, W1, acc1, Af, W2);
    run(Af, W2, acc2, nullptr, nullptr);

    #pragma unroll
    for (int m = 0; m < 4; m++) {
        int row = bm + wr + m * 16 + lk * 4;
        #pragma unroll
        for (int n = 0; n < 4; n++) {
            int col = bn + wc + n * 16 + lr;
            float vb1 = b1[col], vb2 = b2[col];
            #pragma unroll
            for (int r = 0; r < 4; r++) {
                float v = b2f(Am[(size_t)(row + r) * DD + col])
                        + fmaxf(acc1[m][n][r] + vb1, 0.f)
                        + fmaxf(acc2[m][n][r] + vb2, 0.f);
                out[(size_t)(row + r) * DD + col] = v;
            }
        }
    }
}

// ---------------------------------------------------------------------------
// Counting sort machinery
__global__ void hist_kernel(const int* __restrict__ s_idx, const int* __restrict__ o_idx,
                            const int* __restrict__ c_idx,
                            int* cntS, int* cntO, int* cntC) {
    int e = blockIdx.x * blockDim.x + threadIdx.x;
    if (e >= EE) return;
    atomicAdd(&cntS[s_idx[e]], 1);
    atomicAdd(&cntO[o_idx[e]], 1);
    atomicAdd(&cntC[c_idx[e]], 1);
}

__global__ __launch_bounds__(1024) void scan3_kernel(
        const int* __restrict__ cntS, const int* __restrict__ cntO,
        const int* __restrict__ cntC,
        int* __restrict__ startS, int* __restrict__ startO, int* __restrict__ startC) {
    const int* cnt; int* start; int n;
    if (blockIdx.x == 0)      { cnt = cntS; start = startS; n = NN; }
    else if (blockIdx.x == 1) { cnt = cntO; start = startO; n = NN; }
    else                      { cnt = cntC; start = startC; n = PP; }
    __shared__ int sh[1024];
    int t = threadIdx.x;
    int per = n >> 10;
    int base = t * per;
    int s = 0;
    for (int i = 0; i < per; i++) s += cnt[base + i];
    sh[t] = s;
    __syncthreads();
    for (int off = 1; off < 1024; off <<= 1) {
        int v = (t >= off) ? sh[t - off] : 0;
        __syncthreads();
        sh[t] += v;
        __syncthreads();
    }
    int ex = (t == 0) ? 0 : sh[t - 1];
    for (int i = 0; i < per; i++) { start[base + i] = ex; ex += cnt[base + i]; }
    if (t == 1023) start[n] = ex;
}

// Scatter now emits per-edge CSR positions (gate_kernel writes packed entries).
__global__ void scatter_kernel(const int* __restrict__ s_idx, const int* __restrict__ o_idx,
                               const int* __restrict__ c_idx,
                               const int* __restrict__ startS, const int* __restrict__ startO,
                               const int* __restrict__ startC,
                               int* curS, int* curO, int* curC,
                               int* posS, int* posO, int* posC) {
    int e = blockIdx.x * blockDim.x + threadIdx.x;
    if (e >= EE) return;
    int s = s_idx[e];
    posS[e] = startS[s] + atomicAdd(&curS[s], 1);
    int o = o_idx[e];
    posO[e] = startO[o] + atomicAdd(&curO[o], 1);
    int c = c_idx[e];
    posC[e] = startC[c] + atomicAdd(&curC[c], 1);
}

// ---------------------------------------------------------------------------
// Per-edge gates; writes packed CSR entries directly (no gates[] round trip).
__global__ __launch_bounds__(256) void gate_kernel(
        const int* __restrict__ s_idx, const int* __restrict__ o_idx,
        const int* __restrict__ c_idx,
        const int* __restrict__ posS, const int* __restrict__ posO,
        const int* __restrict__ posC,
        const ushort* __restrict__ Ti, const ushort* __restrict__ Tp,
        int2* __restrict__ pkS, int2* __restrict__ pkO, int4* __restrict__ pkC) {
    int gid = blockIdx.x * 256 + threadIdx.x;
    int e = gid >> 6, lane = gid & 63;
    if (e >= EE) return;
    int s = s_idx[e], o = o_idx[e], c = c_idx[e];
    const unsigned int* tpc = (const unsigned int*)(Tp + (size_t)c * G4);
    const unsigned int* tis = (const unsigned int*)(Ti + (size_t)s * G4);
    const unsigned int* tio = (const unsigned int*)(Ti + (size_t)o * G4);
    auto pairSig = [](unsigned int a, unsigned int b) {
        float lo = __uint_as_float(a << 16) + __uint_as_float(b << 16);
        float hi = __uint_as_float(a & 0xffff0000u) + __uint_as_float(b & 0xffff0000u);
        return sigmoid_relu(lo) + sigmoid_relu(hi);
    };
    float s0 = pairSig(tpc[lane],       tis[lane]);
    float s1 = pairSig(tpc[64 + lane],  tio[64 + lane]);
    float s2 = pairSig(tpc[128 + lane], tio[128 + lane]);
    float s3 = pairSig(tpc[192 + lane], tis[192 + lane]);
    #pragma unroll
    for (int off = 32; off; off >>= 1) {
        s0 += __shfl_xor(s0, off);
        s1 += __shfl_xor(s1, off);
        s2 += __shfl_xor(s2, off);
        s3 += __shfl_xor(s3, off);
    }
    if (lane == 0) {
        const float inv = 1.0f / 128.0f;
        pkS[posS[e]] = make_int2(c, __float_as_int(s0 * inv));
        pkO[posO[e]] = make_int2(c, __float_as_int(s1 * inv));
        pkC[posC[e]] = make_int4(o, s, __float_as_int(s2 * inv), __float_as_int(s3 * inv));
    }
}

// ---------------------------------------------------------------------------
__device__ __forceinline__ void accum8(float* acc, uint4 v, float g) {
    acc[0] += g * __uint_as_float(v.x << 16);
    acc[1] += g * __uint_as_float(v.x & 0xffff0000u);
    acc[2] += g * __uint_as_float(v.y << 16);
    acc[3] += g * __uint_as_float(v.y & 0xffff0000u);
    acc[4] += g * __uint_as_float(v.z << 16);
    acc[5] += g * __uint_as_float(v.z & 0xffff0000u);
    acc[6] += g * __uint_as_float(v.w << 16);
    acc[7] += g * __uint_as_float(v.w & 0xffff0000u);
}

// Segment mean, inst side. Block = 4 waves = 2 nodes; per node: S-wave + O-wave.
__global__ __launch_bounds__(256) void seg_inst_kernel(
        const ushort* __restrict__ phraB,
        const int2* __restrict__ pkS, const int* __restrict__ startS,
        const int2* __restrict__ pkO, const int* __restrict__ startO,
        ushort* __restrict__ msgB) {
    __shared__ float lds[4][64 * 17];
    int w = threadIdx.x >> 6, lane = threadIdx.x & 63;
    int node = blockIdx.x * 2 + (w >> 1);
    const int2* pk_list = (w & 1) ? pkO : pkS;
    const int*  start   = (w & 1) ? startO : startS;
    int b = start[node], e = start[node + 1];
    float acc[16];
    #pragma unroll
    for (int j = 0; j < 16; j++) acc[j] = 0.f;
    if (b < e) {
        int2 pk = pk_list[b];
        const uint4* r = (const uint4*)(phraB + (size_t)pk.x * DD) + lane;
        uint4 c0 = r[0], c1 = r[64];
        for (int i = b + 1; i < e; i++) {
            int2 pkn = pk_list[i];
            const uint4* rn = (const uint4*)(phraB + (size_t)pkn.x * DD) + lane;
            uint4 n0 = rn[0], n1 = rn[64];
            float g = __int_as_float(pk.y);
            accum8(acc, c0, g); accum8(acc + 8, c1, g);
            pk = pkn; c0 = n0; c1 = n1;
        }
        float g = __int_as_float(pk.y);
        accum8(acc, c0, g); accum8(acc + 8, c1, g);
    }
    float scale = 0.5f / (float)max(e - b, 1);
    #pragma unroll
    for (int j = 0; j < 16; j++) lds[w][lane * 17 + j] = acc[j] * scale;
    __syncthreads();
    int u = threadIdx.x & 127;
    int outnode = blockIdx.x * 2 + (threadIdx.x >> 7);
    int w0 = (threadIdx.x >> 7) << 1;
    int off = (u & 63) * 17 + (u >> 6) * 8;
    float4 a0 = *(const float4*)&lds[w0][off];
    float4 a1 = *(const float4*)&lds[w0][off + 4];
    float4 b0 = *(const float4*)&lds[w0 + 1][off];
    float4 b1 = *(const float4*)&lds[w0 + 1][off + 4];
    uint4 o;
    o.x = pack2(a0.x + b0.x, a0.y + b0.y);
    o.y = pack2(a0.z + b0.z, a0.w + b0.w);
    o.z = pack2(a1.x + b1.x, a1.y + b1.y);
    o.w = pack2(a1.z + b1.z, a1.w + b1.w);
    *(uint4*)&msgB[(size_t)outnode * DD + u * 8] = o;
}

// Segment mean, phra side. Block = 4 waves = 2 phrases; 2 waves split edges.
__global__ __launch_bounds__(256) void seg_phra_kernel(
        const ushort* __restrict__ instB,
        const int4* __restrict__ pkC, const int* __restrict__ startC,
        ushort* __restrict__ msgB) {
    __shared__ float lds[4][64 * 17];
    int w = threadIdx.x >> 6, lane = threadIdx.x & 63;
    int p = blockIdx.x * 2 + (w >> 1);
    int half = w & 1;
    int cb = startC[p], ce = startC[p + 1];
    float acc[16];
    #pragma unroll
    for (int j = 0; j < 16; j++) acc[j] = 0.f;
    int i0 = cb + half;
    if (i0 < ce) {
        int4 pk = pkC[i0];
        const uint4* ro = (const uint4*)(instB + (size_t)pk.x * DD) + lane;
        const uint4* rs = (const uint4*)(instB + (size_t)pk.y * DD) + lane;
        uint4 o0 = ro[0], o1 = ro[64], s0 = rs[0], s1 = rs[64];
        for (int i = i0 + 2; i < ce; i += 2) {
            int4 pkn = pkC[i];
            const uint4* rno = (const uint4*)(instB + (size_t)pkn.x * DD) + lane;
            const uint4* rns = (const uint4*)(instB + (size_t)pkn.y * DD) + lane;
            uint4 no0 = rno[0], no1 = rno[64], ns0 = rns[0], ns1 = rns[64];
            float go = __int_as_float(pk.z), gs = __int_as_float(pk.w);
            accum8(acc, o0, go); accum8(acc + 8, o1, go);
            accum8(acc, s0, gs); accum8(acc + 8, s1, gs);
            pk = pkn; o0 = no0; o1 = no1; s0 = ns0; s1 = ns1;
        }
        float go = __int_as_float(pk.z), gs = __int_as_float(pk.w);
        accum8(acc, o0, go); accum8(acc + 8, o1, go);
        accum8(acc, s0, gs); accum8(acc + 8, s1, gs);
    }
    float scale = 0.5f / (float)max(ce - cb, 1);
    #pragma unroll
    for (int j = 0; j < 16; j++) lds[w][lane * 17 + j] = acc[j] * scale;
    __syncthreads();
    int u = threadIdx.x & 127;
    int outp = blockIdx.x * 2 + (threadIdx.x >> 7);
    int w0 = (threadIdx.x >> 7) << 1;
    int off = (u & 63) * 17 + (u >> 6) * 8;
    float4 a0 = *(const float4*)&lds[w0][off];
    float4 a1 = *(const float4*)&lds[w0][off + 4];
    float4 b0 = *(const float4*)&lds[w0 + 1][off];
    float4 b1 = *(const float4*)&lds[w0 + 1][off + 4];
    uint4 o;
    o.x = pack2(a0.x + b0.x, a0.y + b0.y);
    o.y = pack2(a0.z + b0.z, a0.w + b0.w);
    o.z = pack2(a1.x + b1.x, a1.y + b1.y);
    o.w = pack2(a1.z + b1.z, a1.w + b1.w);
    *(uint4*)&msgB[(size_t)outp * DD + u * 8] = o;
}

// ---------------------------------------------------------------------------
extern "C" void kernel_launch(void* const* d_in, const int* in_sizes, int n_in,
                              void* d_out, int out_size, void* d_ws, size_t ws_size,
                              hipStream_t stream) {
    (void)in_sizes; (void)n_in; (void)out_size; (void)ws_size;
    const float* inst_feat = (const float*)d_in[0];
    const float* phra_feat = (const float*)d_in[1];
    const int*   conn      = (const int*)d_in[2];
    const int*   clu       = (const int*)d_in[3];
    const float* psW = (const float*)d_in[4];  const float* psB = (const float*)d_in[5];
    const float* poW = (const float*)d_in[6];  const float* poB = (const float*)d_in[7];
    const float* opW = (const float*)d_in[8];  const float* opB = (const float*)d_in[9];
    const float* spW = (const float*)d_in[10]; const float* spB = (const float*)d_in[11];
    const float* iw1W = (const float*)d_in[12]; const float* iw1B = (const float*)d_in[13];
    const float* iw2W = (const float*)d_in[14]; const float* iw2B = (const float*)d_in[15];
    const float* pw1W = (const float*)d_in[16]; const float* pw1B = (const float*)d_in[17];
    const float* pw2W = (const float*)d_in[18]; const float* pw2B = (const float*)d_in[19];
    const int* s_idx = conn;
    const int* o_idx = conn + EE;

    char* ws = (char*)d_ws;
    size_t off = 0;
    auto alloc = [&](size_t bytes) {
        char* p = ws + off;
        off += (bytes + 255) & ~(size_t)255;
        return p;
    };
    ushort* instB = (ushort*)alloc((size_t)NN * DD * 2);
    ushort* phraB = (ushort*)alloc((size_t)PP * DD * 2);
    ushort* WiT   = (ushort*)alloc((size_t)G4 * DD * 2);
    ushort* WpT   = (ushort*)alloc((size_t)G4 * DD * 2);
    ushort* iw1T  = (ushort*)alloc((size_t)DD * DD * 2);
    ushort* iw2T  = (ushort*)alloc((size_t)DD * DD * 2);
    ushort* pw1T  = (ushort*)alloc((size_t)DD * DD * 2);
    ushort* pw2T  = (ushort*)alloc((size_t)DD * DD * 2);
    float* biascat = (float*)alloc(G4 * 4);
    ushort* TiB   = (ushort*)alloc((size_t)NN * G4 * 2);
    ushort* TpB   = (ushort*)alloc((size_t)PP * G4 * 2);
    int* cntBlock = (int*)alloc((size_t)(2 * (NN + NN + PP)) * 4);
    int* cntS = cntBlock;      int* cntO = cntS + NN;  int* cntC = cntO + NN;
    int* curS = cntC + PP;     int* curO = curS + NN;  int* curC = curO + NN;
    int* startS = (int*)alloc((NN + 1) * 4);
    int* startO = (int*)alloc((NN + 1) * 4);
    int* startC = (int*)alloc((PP + 1) * 4);
    int* posS   = (int*)alloc((size_t)EE * 4);
    int* posO   = (int*)alloc((size_t)EE * 4);
    int* posC   = (int*)alloc((size_t)EE * 4);
    int2* pkS   = (int2*)alloc((size_t)EE * 8);
    int2* pkO   = (int2*)alloc((size_t)EE * 8);
    int4* pkC   = (int4*)alloc((size_t)EE * 16);
    ushort* imsgB = (ushort*)alloc((size_t)NN * DD * 2);
    ushort* pmsgB = (ushort*)alloc((size_t)PP * DD * 2);

    float* inst_out = (float*)d_out;
    float* phra_out = inst_out + (size_t)NN * DD;

    hipMemsetAsync(cntBlock, 0, (size_t)(2 * (NN + NN + PP)) * 4, stream);

    // Fused prep: feature bf16 casts + gate-weight pack + refine-weight transpose
    prep_kernel<<<NB_F2B + NB_PACK + NB_WT, 256, 0, stream>>>(
        inst_feat, phra_feat, instB, phraB,
        psW, poW, opW, spW, psB, poB, opB, spB, WiT, WpT, biascat,
        iw1W, iw2W, pw1W, pw2W, iw1T, iw2T, pw1T, pw2T);

    // CSR build
    hist_kernel<<<EE / 256, 256, 0, stream>>>(s_idx, o_idx, clu, cntS, cntO, cntC);
    scan3_kernel<<<3, 1024, 0, stream>>>(cntS, cntO, cntC, startS, startO, startC);
    scatter_kernel<<<EE / 256, 256, 0, stream>>>(s_idx, o_idx, clu, startS, startO, startC,
                                                 curS, curO, curC, posS, posO, posC);

    // Gate tables (bf16 MFMA, bias folded into Tp)
    mfma_tables_kernel<<<dim3((NN + PP) / 128, G4 / 64), 256, 0, stream>>>(
        instB, WiT, phraB, WpT, biascat, TiB, TpB);

    // Gates -> packed CSR entries directly
    gate_kernel<<<(EE * 64) / 256, 256, 0, stream>>>(s_idx, o_idx, clu, posS, posO, posC,
                                                     TiB, TpB, pkS, pkO, pkC);

    // Segment means
    seg_inst_kernel<<<NN / 2, 256, 0, stream>>>(phraB, pkS, startS, pkO, startO, imsgB);
    seg_phra_kernel<<<PP / 2, 256, 0, stream>>>(instB, pkC, startC, pmsgB);

    // Fused refine (both sides, continuous counted-vmcnt pipeline)
    mfma_refine_kernel<<<dim3((NN + PP) / 128, DD / 128), 256, 0, stream>>>(
        imsgB, instB, iw1T, iw2T, iw1B, iw2B, inst_out,
        pmsgB, phraB, pw1T, pw2T, pw1B, pw2B, phra_out);
}

// Round 6
// 177.512 us; speedup vs baseline: 5.0440x; 1.0479x over previous
//
#include <hip/hip_runtime.h>
#include <math.h>

// Problem constants (fixed by the reference)
constexpr int NN  = 4096;   // instances
constexpr int PP  = 2048;   // phrases
constexpr int EE  = 65536;  // edges
constexpr int DD  = 1024;   // feature dim
constexpr int OUTF = 128;   // gate MLP out dim
constexpr int G4  = 512;    // 4 gates * 128

typedef __attribute__((ext_vector_type(8))) short short8v;
typedef __attribute__((ext_vector_type(4))) float f32x4;

__device__ __forceinline__ float sigmoid_relu(float z) {
    z = fmaxf(z, 0.0f);
    return 1.0f / (1.0f + __expf(-z));
}
__device__ __forceinline__ float b2f(ushort u) {
    return __uint_as_float(((unsigned int)u) << 16);
}
__device__ __forceinline__ ushort f2b(float f) {  // RNE
    unsigned int x = __float_as_uint(f);
    return (ushort)((x + 0x7fffu + ((x >> 16) & 1u)) >> 16);
}
__device__ __forceinline__ unsigned int pack2(float a, float b) {
    return (unsigned int)f2b(a) | ((unsigned int)f2b(b) << 16);
}

#define GLD16(gptr, lptr) \
    __builtin_amdgcn_global_load_lds((__attribute__((address_space(1))) const void*)(gptr), \
                                     (__attribute__((address_space(3))) void*)(lptr), 16, 0, 0)
// Counted-vmcnt pipeline primitives (T4): keep just-issued loads in flight.
#define ASM_VMCNT(n) asm volatile("s_waitcnt vmcnt(" #n ")" ::: "memory")
#define BARRIER() do { asm volatile("" ::: "memory"); \
                       __builtin_amdgcn_s_barrier();  \
                       asm volatile("" ::: "memory"); } while (0)

// ---------------------------------------------------------------------------
// Fused prep: f32->bf16 features, gate-weight pack, refine-weight transpose.
constexpr int NB_F2B  = (NN + PP) * DD / 4 / 256;  // 6144
constexpr int NB_PACK = G4 * DD / 256;             // 2048
constexpr int NB_WT   = 4 * (DD / 64) * (DD / 64); // 1024

__global__ __launch_bounds__(256) void prep_kernel(
        const float* __restrict__ instF, const float* __restrict__ phraF,
        ushort* __restrict__ instB, ushort* __restrict__ phraB,
        const float* __restrict__ psW, const float* __restrict__ poW,
        const float* __restrict__ opW, const float* __restrict__ spW,
        const float* __restrict__ psB, const float* __restrict__ poB,
        const float* __restrict__ opB, const float* __restrict__ spB,
        ushort* __restrict__ WiT, ushort* __restrict__ WpT,
        float* __restrict__ biascat,
        const float* __restrict__ W0, const float* __restrict__ W1,
        const float* __restrict__ W2, const float* __restrict__ W3,
        ushort* __restrict__ T0, ushort* __restrict__ T1,
        ushort* __restrict__ T2, ushort* __restrict__ T3) {
    __shared__ float tile[64][65];
    int b = blockIdx.x, t = threadIdx.x;
    if (b < NB_F2B) {
        int i = b * 256 + t;
        constexpr int na4 = NN * DD / 4;
        if (i < na4) {
            float4 v = ((const float4*)instF)[i];
            ushort4 u; u.x = f2b(v.x); u.y = f2b(v.y); u.z = f2b(v.z); u.w = f2b(v.w);
            ((ushort4*)instB)[i] = u;
        } else {
            int j = i - na4;
            float4 v = ((const float4*)phraF)[j];
            ushort4 u; u.x = f2b(v.x); u.y = f2b(v.y); u.z = f2b(v.z); u.w = f2b(v.w);
            ((ushort4*)phraB)[j] = u;
        }
        return;
    }
    b -= NB_F2B;
    if (b < NB_PACK) {
        int idx = b * 256 + t;
        int n = idx >> 10, k = idx & 1023;
        int g = n >> 7, j = n & 127;
        float wi, wp;
        if (g == 0)      { wi = psW[(size_t)(DD + k) * OUTF + j]; wp = psW[(size_t)k * OUTF + j]; }
        else if (g == 1) { wi = poW[(size_t)(DD + k) * OUTF + j]; wp = poW[(size_t)k * OUTF + j]; }
        else if (g == 2) { wi = opW[(size_t)k * OUTF + j];        wp = opW[(size_t)(DD + k) * OUTF + j]; }
        else             { wi = spW[(size_t)k * OUTF + j];        wp = spW[(size_t)(DD + k) * OUTF + j]; }
        WiT[idx] = f2b(wi);
        WpT[idx] = f2b(wp);
        if (idx < G4) {
            int gg = idx >> 7, jj = idx & 127;
            biascat[idx] = (gg == 0) ? psB[jj] : (gg == 1) ? poB[jj]
                         : (gg == 2) ? opB[jj] : spB[jj];
        }
        return;
    }
    b -= NB_PACK;
    int z = b >> 8, rest = b & 255;
    const float* W = (z == 0) ? W0 : (z == 1) ? W1 : (z == 2) ? W2 : W3;
    ushort*      T = (z == 0) ? T0 : (z == 1) ? T1 : (z == 2) ? T2 : T3;
    int k0 = (rest & 15) * 64, n0 = (rest >> 4) * 64;
    int tx = t & 63, ty = t >> 6;
    #pragma unroll
    for (int i = 0; i < 64; i += 4)
        tile[ty + i][tx] = W[(size_t)(k0 + ty + i) * DD + n0 + tx];
    __syncthreads();
    #pragma unroll
    for (int i = 0; i < 64; i += 4)
        T[(size_t)(n0 + ty + i) * DD + k0 + tx] = f2b(tile[tx][ty + i]);
}

// ---------------------------------------------------------------------------
// Pipelined MFMA GEMM building blocks. A-tile 128 rows; B-tile BROWS rows.
// BK=64, XOR-swizzled linear LDS (rule 21).
template<int BROWS>
__device__ __forceinline__ void stage_tiles(const ushort* __restrict__ A,
                                            const ushort* __restrict__ BT,
                                            int bm, int bn, int k0,
                                            ushort* Asl, ushort* Bsl, int t) {
    #pragma unroll
    for (int r = 0; r < 4; r++) {
        int ch = r * 256 + t;
        int row = ch >> 3;
        int sw = ((ch & 7) ^ (row & 7)) << 3;
        GLD16(A + (size_t)(bm + row) * DD + k0 + sw, &Asl[ch * 8]);
    }
    #pragma unroll
    for (int r = 0; r < BROWS / 32; r++) {
        int ch = r * 256 + t;
        int row = ch >> 3;
        int sw = ((ch & 7) ^ (row & 7)) << 3;
        GLD16(BT + (size_t)(bn + row) * DD + k0 + sw, &Bsl[ch * 8]);
    }
}

template<int NACC>
__device__ __forceinline__ void compute_tiles(const ushort* Asl, const ushort* Bsl,
                                              f32x4 (&acc)[4][NACC],
                                              int wr, int wc, int lr, int lk) {
    #pragma unroll
    for (int kk = 0; kk < 2; kk++) {
        int ch16 = kk * 4 + lk;
        short8v a[4], b[NACC];
        #pragma unroll
        for (int m = 0; m < 4; m++) {
            int ra = wr + m * 16 + lr;
            a[m] = *(const short8v*)&Asl[ra * 64 + ((ch16 ^ (ra & 7)) << 3)];
        }
        #pragma unroll
        for (int n = 0; n < NACC; n++) {
            int rb = wc + n * 16 + lr;
            b[n] = *(const short8v*)&Bsl[rb * 64 + ((ch16 ^ (rb & 7)) << 3)];
        }
        #pragma unroll
        for (int m = 0; m < 4; m++)
            #pragma unroll
            for (int n = 0; n < NACC; n++)
                acc[m][n] = __builtin_amdgcn_mfma_f32_16x16x32_bf16(a[m], b[n], acc[m][n], 0, 0, 0);
    }
}

// ---------------------------------------------------------------------------
// Gate tables, 128x64 tile, counted-vmcnt 2-buffer pipeline (plain mapping).
__global__ __launch_bounds__(256) void mfma_tables_kernel(
        const ushort* __restrict__ instB, const ushort* __restrict__ WiT,
        const ushort* __restrict__ phraB, const ushort* __restrict__ WpT,
        const float* __restrict__ biascat,
        ushort* __restrict__ TiB, ushort* __restrict__ TpB) {
    __shared__ ushort Asl[2][128 * 64];
    __shared__ ushort Bsl[2][64 * 64];
    int bx = blockIdx.x;
    const ushort *A, *BT; ushort* C; const float* bias;
    if (bx < NN / 128) { A = instB; BT = WiT; C = TiB; bias = nullptr; }
    else { bx -= NN / 128; A = phraB; BT = WpT; C = TpB; bias = biascat; }
    int bm = bx * 128, bn = blockIdx.y * 64;
    int t = threadIdx.x;
    const int lane = t & 63, w = t >> 6;
    const int wr = (w >> 1) * 64, wc = (w & 1) * 32;
    const int lr = lane & 15, lk = lane >> 4;
    f32x4 acc[4][2] = {};

    int cur = 0;
    stage_tiles<64>(A, BT, bm, bn, 0, Asl[0], Bsl[0], t);
    for (int k0 = 0; k0 < DD; k0 += 64) {
        int nxt = cur ^ 1;
        if (k0 + 64 < DD) {
            stage_tiles<64>(A, BT, bm, bn, k0 + 64, Asl[nxt], Bsl[nxt], t);
            ASM_VMCNT(6);
        } else {
            ASM_VMCNT(0);
        }
        BARRIER();
        compute_tiles<2>(Asl[cur], Bsl[cur], acc, wr, wc, lr, lk);
        BARRIER();
        cur = nxt;
    }
    #pragma unroll
    for (int m = 0; m < 4; m++) {
        int row = bm + wr + m * 16 + lk * 4;
        #pragma unroll
        for (int n = 0; n < 2; n++) {
            int col = bn + wc + n * 16 + lr;
            float bv = bias ? bias[col] : 0.f;
            #pragma unroll
            for (int r = 0; r < 4; r++)
                C[(size_t)(row + r) * G4 + col] = f2b(acc[m][n][r] + bv);
        }
    }
}

// ---------------------------------------------------------------------------
// Fused refine: out = msg + relu(msg@W1+b1) + relu(feat@W2+b2).
// 128x64 tile (grid 48x16 = 768 blocks, 3 blocks/CU at 48 KB LDS),
// continuous counted-vmcnt pipeline across both K=1024 passes.
__global__ __launch_bounds__(256) void mfma_refine_kernel(
        const ushort* __restrict__ imsgB, const ushort* __restrict__ instB,
        const ushort* __restrict__ iw1T, const ushort* __restrict__ iw2T,
        const float* __restrict__ ib1, const float* __restrict__ ib2,
        float* __restrict__ iout,
        const ushort* __restrict__ pmsgB, const ushort* __restrict__ phraB,
        const ushort* __restrict__ pw1T, const ushort* __restrict__ pw2T,
        const float* __restrict__ pb1, const float* __restrict__ pb2,
        float* __restrict__ pout) {
    __shared__ ushort Asl[2][128 * 64];
    __shared__ ushort Bsl[2][64 * 64];
    int bx = blockIdx.x;
    const ushort *Am, *Af, *W1, *W2; const float *b1, *b2; float* out;
    if (bx < NN / 128) {
        Am = imsgB; Af = instB; W1 = iw1T; W2 = iw2T; b1 = ib1; b2 = ib2; out = iout;
    } else {
        bx -= NN / 128;
        Am = pmsgB; Af = phraB; W1 = pw1T; W2 = pw2T; b1 = pb1; b2 = pb2; out = pout;
    }
    int bm = bx * 128, bn = blockIdx.y * 64;
    int t = threadIdx.x;
    const int lane = t & 63, w = t >> 6;
    const int wr = (w >> 1) * 64, wc = (w & 1) * 32;
    const int lr = lane & 15, lk = lane >> 4;
    f32x4 acc1[4][2] = {};
    f32x4 acc2[4][2] = {};

    int cur = 0;
    stage_tiles<64>(Am, W1, bm, bn, 0, Asl[0], Bsl[0], t);
    auto run = [&](const ushort* A, const ushort* B, f32x4 (&acc)[4][2],
                   const ushort* An, const ushort* Bn) {
        for (int k0 = 0; k0 < DD; k0 += 64) {
            int nxt = cur ^ 1;
            if (k0 + 64 < DD) {
                stage_tiles<64>(A, B, bm, bn, k0 + 64, Asl[nxt], Bsl[nxt], t);
                ASM_VMCNT(6);
            } else if (An) {
                stage_tiles<64>(An, Bn, bm, bn, 0, Asl[nxt], Bsl[nxt], t);
                ASM_VMCNT(6);
            } else {
                ASM_VMCNT(0);
            }
            BARRIER();
            compute_tiles<2>(Asl[cur], Bsl[cur], acc, wr, wc, lr, lk);
            BARRIER();
            cur = nxt;
        }
    };
    run(Am, W1, acc1, Af, W2);
    run(Af, W2, acc2, nullptr, nullptr);

    #pragma unroll
    for (int m = 0; m < 4; m++) {
        int row = bm + wr + m * 16 + lk * 4;
        #pragma unroll
        for (int n = 0; n < 2; n++) {
            int col = bn + wc + n * 16 + lr;
            float vb1 = b1[col], vb2 = b2[col];
            #pragma unroll
            for (int r = 0; r < 4; r++) {
                float v = b2f(Am[(size_t)(row + r) * DD + col])
                        + fmaxf(acc1[m][n][r] + vb1, 0.f)
                        + fmaxf(acc2[m][n][r] + vb2, 0.f);
                out[(size_t)(row + r) * DD + col] = v;
            }
        }
    }
}

// ---------------------------------------------------------------------------
// Counting sort machinery
__global__ void hist_kernel(const int* __restrict__ s_idx, const int* __restrict__ o_idx,
                            const int* __restrict__ c_idx,
                            int* cntS, int* cntO, int* cntC) {
    int e = blockIdx.x * blockDim.x + threadIdx.x;
    if (e >= EE) return;
    atomicAdd(&cntS[s_idx[e]], 1);
    atomicAdd(&cntO[o_idx[e]], 1);
    atomicAdd(&cntC[c_idx[e]], 1);
}

__global__ __launch_bounds__(1024) void scan3_kernel(
        const int* __restrict__ cntS, const int* __restrict__ cntO,
        const int* __restrict__ cntC,
        int* __restrict__ startS, int* __restrict__ startO, int* __restrict__ startC) {
    const int* cnt; int* start; int n;
    if (blockIdx.x == 0)      { cnt = cntS; start = startS; n = NN; }
    else if (blockIdx.x == 1) { cnt = cntO; start = startO; n = NN; }
    else                      { cnt = cntC; start = startC; n = PP; }
    __shared__ int sh[1024];
    int t = threadIdx.x;
    int per = n >> 10;
    int base = t * per;
    int s = 0;
    for (int i = 0; i < per; i++) s += cnt[base + i];
    sh[t] = s;
    __syncthreads();
    for (int off = 1; off < 1024; off <<= 1) {
        int v = (t >= off) ? sh[t - off] : 0;
        __syncthreads();
        sh[t] += v;
        __syncthreads();
    }
    int ex = (t == 0) ? 0 : sh[t - 1];
    for (int i = 0; i < per; i++) { start[base + i] = ex; ex += cnt[base + i]; }
    if (t == 1023) start[n] = ex;
}

// Scatter emits per-edge CSR positions (gate_kernel writes packed entries).
__global__ void scatter_kernel(const int* __restrict__ s_idx, const int* __restrict__ o_idx,
                               const int* __restrict__ c_idx,
                               const int* __restrict__ startS, const int* __restrict__ startO,
                               const int* __restrict__ startC,
                               int* curS, int* curO, int* curC,
                               int* posS, int* posO, int* posC) {
    int e = blockIdx.x * blockDim.x + threadIdx.x;
    if (e >= EE) return;
    int s = s_idx[e];
    posS[e] = startS[s] + atomicAdd(&curS[s], 1);
    int o = o_idx[e];
    posO[e] = startO[o] + atomicAdd(&curO[o], 1);
    int c = c_idx[e];
    posC[e] = startC[c] + atomicAdd(&curC[c], 1);
}

// ---------------------------------------------------------------------------
// Per-edge gates; writes packed CSR entries directly (no gates[] round trip).
__global__ __launch_bounds__(256) void gate_kernel(
        const int* __restrict__ s_idx, const int* __restrict__ o_idx,
        const int* __restrict__ c_idx,
        const int* __restrict__ posS, const int* __restrict__ posO,
        const int* __restrict__ posC,
        const ushort* __restrict__ Ti, const ushort* __restrict__ Tp,
        int2* __restrict__ pkS, int2* __restrict__ pkO, int4* __restrict__ pkC) {
    int gid = blockIdx.x * 256 + threadIdx.x;
    int e = gid >> 6, lane = gid & 63;
    if (e >= EE) return;
    int s = s_idx[e], o = o_idx[e], c = c_idx[e];
    const unsigned int* tpc = (const unsigned int*)(Tp + (size_t)c * G4);
    const unsigned int* tis = (const unsigned int*)(Ti + (size_t)s * G4);
    const unsigned int* tio = (const unsigned int*)(Ti + (size_t)o * G4);
    auto pairSig = [](unsigned int a, unsigned int b) {
        float lo = __uint_as_float(a << 16) + __uint_as_float(b << 16);
        float hi = __uint_as_float(a & 0xffff0000u) + __uint_as_float(b & 0xffff0000u);
        return sigmoid_relu(lo) + sigmoid_relu(hi);
    };
    float s0 = pairSig(tpc[lane],       tis[lane]);
    float s1 = pairSig(tpc[64 + lane],  tio[64 + lane]);
    float s2 = pairSig(tpc[128 + lane], tio[128 + lane]);
    float s3 = pairSig(tpc[192 + lane], tis[192 + lane]);
    #pragma unroll
    for (int off = 32; off; off >>= 1) {
        s0 += __shfl_xor(s0, off);
        s1 += __shfl_xor(s1, off);
        s2 += __shfl_xor(s2, off);
        s3 += __shfl_xor(s3, off);
    }
    if (lane == 0) {
        const float inv = 1.0f / 128.0f;
        pkS[posS[e]] = make_int2(c, __float_as_int(s0 * inv));
        pkO[posO[e]] = make_int2(c, __float_as_int(s1 * inv));
        pkC[posC[e]] = make_int4(o, s, __float_as_int(s2 * inv), __float_as_int(s3 * inv));
    }
}

// ---------------------------------------------------------------------------
__device__ __forceinline__ void accum8(float* acc, uint4 v, float g) {
    acc[0] += g * __uint_as_float(v.x << 16);
    acc[1] += g * __uint_as_float(v.x & 0xffff0000u);
    acc[2] += g * __uint_as_float(v.y << 16);
    acc[3] += g * __uint_as_float(v.y & 0xffff0000u);
    acc[4] += g * __uint_as_float(v.z << 16);
    acc[5] += g * __uint_as_float(v.z & 0xffff0000u);
    acc[6] += g * __uint_as_float(v.w << 16);
    acc[7] += g * __uint_as_float(v.w & 0xffff0000u);
}

// Segment mean, inst side. Block = 4 waves = 2 nodes; per node: S-wave + O-wave.
__global__ __launch_bounds__(256) void seg_inst_kernel(
        const ushort* __restrict__ phraB,
        const int2* __restrict__ pkS, const int* __restrict__ startS,
        const int2* __restrict__ pkO, const int* __restrict__ startO,
        ushort* __restrict__ msgB) {
    __shared__ float lds[4][64 * 17];
    int w = threadIdx.x >> 6, lane = threadIdx.x & 63;
    int node = blockIdx.x * 2 + (w >> 1);
    const int2* pk_list = (w & 1) ? pkO : pkS;
    const int*  start   = (w & 1) ? startO : startS;
    int b = start[node], e = start[node + 1];
    float acc[16];
    #pragma unroll
    for (int j = 0; j < 16; j++) acc[j] = 0.f;
    if (b < e) {
        int2 pk = pk_list[b];
        const uint4* r = (const uint4*)(phraB + (size_t)pk.x * DD) + lane;
        uint4 c0 = r[0], c1 = r[64];
        for (int i = b + 1; i < e; i++) {
            int2 pkn = pk_list[i];
            const uint4* rn = (const uint4*)(phraB + (size_t)pkn.x * DD) + lane;
            uint4 n0 = rn[0], n1 = rn[64];
            float g = __int_as_float(pk.y);
            accum8(acc, c0, g); accum8(acc + 8, c1, g);
            pk = pkn; c0 = n0; c1 = n1;
        }
        float g = __int_as_float(pk.y);
        accum8(acc, c0, g); accum8(acc + 8, c1, g);
    }
    float scale = 0.5f / (float)max(e - b, 1);
    #pragma unroll
    for (int j = 0; j < 16; j++) lds[w][lane * 17 + j] = acc[j] * scale;
    __syncthreads();
    int u = threadIdx.x & 127;
    int outnode = blockIdx.x * 2 + (threadIdx.x >> 7);
    int w0 = (threadIdx.x >> 7) << 1;
    int off = (u & 63) * 17 + (u >> 6) * 8;
    float4 a0 = *(const float4*)&lds[w0][off];
    float4 a1 = *(const float4*)&lds[w0][off + 4];
    float4 b0 = *(const float4*)&lds[w0 + 1][off];
    float4 b1 = *(const float4*)&lds[w0 + 1][off + 4];
    uint4 o;
    o.x = pack2(a0.x + b0.x, a0.y + b0.y);
    o.y = pack2(a0.z + b0.z, a0.w + b0.w);
    o.z = pack2(a1.x + b1.x, a1.y + b1.y);
    o.w = pack2(a1.z + b1.z, a1.w + b1.w);
    *(uint4*)&msgB[(size_t)outnode * DD + u * 8] = o;
}

// Segment mean, phra side. Block = 4 waves = 2 phrases; 2 waves split edges.
__global__ __launch_bounds__(256) void seg_phra_kernel(
        const ushort* __restrict__ instB,
        const int4* __restrict__ pkC, const int* __restrict__ startC,
        ushort* __restrict__ msgB) {
    __shared__ float lds[4][64 * 17];
    int w = threadIdx.x >> 6, lane = threadIdx.x & 63;
    int p = blockIdx.x * 2 + (w >> 1);
    int half = w & 1;
    int cb = startC[p], ce = startC[p + 1];
    float acc[16];
    #pragma unroll
    for (int j = 0; j < 16; j++) acc[j] = 0.f;
    int i0 = cb + half;
    if (i0 < ce) {
        int4 pk = pkC[i0];
        const uint4* ro = (const uint4*)(instB + (size_t)pk.x * DD) + lane;
        const uint4* rs = (const uint4*)(instB + (size_t)pk.y * DD) + lane;
        uint4 o0 = ro[0], o1 = ro[64], s0 = rs[0], s1 = rs[64];
        for (int i = i0 + 2; i < ce; i += 2) {
            int4 pkn = pkC[i];
            const uint4* rno = (const uint4*)(instB + (size_t)pkn.x * DD) + lane;
            const uint4* rns = (const uint4*)(instB + (size_t)pkn.y * DD) + lane;
            uint4 no0 = rno[0], no1 = rno[64], ns0 = rns[0], ns1 = rns[64];
            float go = __int_as_float(pk.z), gs = __int_as_float(pk.w);
            accum8(acc, o0, go); accum8(acc + 8, o1, go);
            accum8(acc, s0, gs); accum8(acc + 8, s1, gs);
            pk = pkn; o0 = no0; o1 = no1; s0 = ns0; s1 = ns1;
        }
        float go = __int_as_float(pk.z), gs = __int_as_float(pk.w);
        accum8(acc, o0, go); accum8(acc + 8, o1, go);
        accum8(acc, s0, gs); accum8(acc + 8, s1, gs);
    }
    float scale = 0.5f / (float)max(ce - cb, 1);
    #pragma unroll
    for (int j = 0; j < 16; j++) lds[w][lane * 17 + j] = acc[j] * scale;
    __syncthreads();
    int u = threadIdx.x & 127;
    int outp = blockIdx.x * 2 + (threadIdx.x >> 7);
    int w0 = (threadIdx.x >> 7) << 1;
    int off = (u & 63) * 17 + (u >> 6) * 8;
    float4 a0 = *(const float4*)&lds[w0][off];
    float4 a1 = *(const float4*)&lds[w0][off + 4];
    float4 b0 = *(const float4*)&lds[w0 + 1][off];
    float4 b1 = *(const float4*)&lds[w0 + 1][off + 4];
    uint4 o;
    o.x = pack2(a0.x + b0.x, a0.y + b0.y);
    o.y = pack2(a0.z + b0.z, a0.w + b0.w);
    o.z = pack2(a1.x + b1.x, a1.y + b1.y);
    o.w = pack2(a1.z + b1.z, a1.w + b1.w);
    *(uint4*)&msgB[(size_t)outp * DD + u * 8] = o;
}

// ---------------------------------------------------------------------------
extern "C" void kernel_launch(void* const* d_in, const int* in_sizes, int n_in,
                              void* d_out, int out_size, void* d_ws, size_t ws_size,
                              hipStream_t stream) {
    (void)in_sizes; (void)n_in; (void)out_size; (void)ws_size;
    const float* inst_feat = (const float*)d_in[0];
    const float* phra_feat = (const float*)d_in[1];
    const int*   conn      = (const int*)d_in[2];
    const int*   clu       = (const int*)d_in[3];
    const float* psW = (const float*)d_in[4];  const float* psB = (const float*)d_in[5];
    const float* poW = (const float*)d_in[6];  const float* poB = (const float*)d_in[7];
    const float* opW = (const float*)d_in[8];  const float* opB = (const float*)d_in[9];
    const float* spW = (const float*)d_in[10]; const float* spB = (const float*)d_in[11];
    const float* iw1W = (const float*)d_in[12]; const float* iw1B = (const float*)d_in[13];
    const float* iw2W = (const float*)d_in[14]; const float* iw2B = (const float*)d_in[15];
    const float* pw1W = (const float*)d_in[16]; const float* pw1B = (const float*)d_in[17];
    const float* pw2W = (const float*)d_in[18]; const float* pw2B = (const float*)d_in[19];
    const int* s_idx = conn;
    const int* o_idx = conn + EE;

    char* ws = (char*)d_ws;
    size_t off = 0;
    auto alloc = [&](size_t bytes) {
        char* p = ws + off;
        off += (bytes + 255) & ~(size_t)255;
        return p;
    };
    ushort* instB = (ushort*)alloc((size_t)NN * DD * 2);
    ushort* phraB = (ushort*)alloc((size_t)PP * DD * 2);
    ushort* WiT   = (ushort*)alloc((size_t)G4 * DD * 2);
    ushort* WpT   = (ushort*)alloc((size_t)G4 * DD * 2);
    ushort* iw1T  = (ushort*)alloc((size_t)DD * DD * 2);
    ushort* iw2T  = (ushort*)alloc((size_t)DD * DD * 2);
    ushort* pw1T  = (ushort*)alloc((size_t)DD * DD * 2);
    ushort* pw2T  = (ushort*)alloc((size_t)DD * DD * 2);
    float* biascat = (float*)alloc(G4 * 4);
    ushort* TiB   = (ushort*)alloc((size_t)NN * G4 * 2);
    ushort* TpB   = (ushort*)alloc((size_t)PP * G4 * 2);
    int* cntBlock = (int*)alloc((size_t)(2 * (NN + NN + PP)) * 4);
    int* cntS = cntBlock;      int* cntO = cntS + NN;  int* cntC = cntO + NN;
    int* curS = cntC + PP;     int* curO = curS + NN;  int* curC = curO + NN;
    int* startS = (int*)alloc((NN + 1) * 4);
    int* startO = (int*)alloc((NN + 1) * 4);
    int* startC = (int*)alloc((PP + 1) * 4);
    int* posS   = (int*)alloc((size_t)EE * 4);
    int* posO   = (int*)alloc((size_t)EE * 4);
    int* posC   = (int*)alloc((size_t)EE * 4);
    int2* pkS   = (int2*)alloc((size_t)EE * 8);
    int2* pkO   = (int2*)alloc((size_t)EE * 8);
    int4* pkC   = (int4*)alloc((size_t)EE * 16);
    ushort* imsgB = (ushort*)alloc((size_t)NN * DD * 2);
    ushort* pmsgB = (ushort*)alloc((size_t)PP * DD * 2);

    float* inst_out = (float*)d_out;
    float* phra_out = inst_out + (size_t)NN * DD;

    hipMemsetAsync(cntBlock, 0, (size_t)(2 * (NN + NN + PP)) * 4, stream);

    // Fused prep: feature bf16 casts + gate-weight pack + refine-weight transpose
    prep_kernel<<<NB_F2B + NB_PACK + NB_WT, 256, 0, stream>>>(
        inst_feat, phra_feat, instB, phraB,
        psW, poW, opW, spW, psB, poB, opB, spB, WiT, WpT, biascat,
        iw1W, iw2W, pw1W, pw2W, iw1T, iw2T, pw1T, pw2T);

    // CSR build
    hist_kernel<<<EE / 256, 256, 0, stream>>>(s_idx, o_idx, clu, cntS, cntO, cntC);
    scan3_kernel<<<3, 1024, 0, stream>>>(cntS, cntO, cntC, startS, startO, startC);
    scatter_kernel<<<EE / 256, 256, 0, stream>>>(s_idx, o_idx, clu, startS, startO, startC,
                                                 curS, curO, curC, posS, posO, posC);

    // Gate tables (bf16 MFMA, bias folded into Tp)
    mfma_tables_kernel<<<dim3((NN + PP) / 128, G4 / 64), 256, 0, stream>>>(
        instB, WiT, phraB, WpT, biascat, TiB, TpB);

    // Gates -> packed CSR entries directly
    gate_kernel<<<(EE * 64) / 256, 256, 0, stream>>>(s_idx, o_idx, clu, posS, posO, posC,
                                                     TiB, TpB, pkS, pkO, pkC);

    // Segment means
    seg_inst_kernel<<<NN / 2, 256, 0, stream>>>(phraB, pkS, startS, pkO, startO, imsgB);
    seg_phra_kernel<<<PP / 2, 256, 0, stream>>>(instB, pkC, startC, pmsgB);

    // Fused refine (128x64 tiles, 768 blocks, counted-vmcnt pipeline)
    mfma_refine_kernel<<<dim3((NN + PP) / 128, DD / 64), 256, 0, stream>>>(
        imsgB, instB, iw1T, iw2T, iw1B, iw2B, inst_out,
        pmsgB, phraB, pw1T, pw2T, pw1B, pw2B, phra_out);
}

// Round 7
// 158.107 us; speedup vs baseline: 5.6630x; 1.1227x over previous
//
#include <hip/hip_runtime.h>
#include <math.h>

// Problem constants (fixed by the reference)
constexpr int NN  = 4096;   // instances
constexpr int PP  = 2048;   // phrases
constexpr int EE  = 65536;  // edges
constexpr int DD  = 1024;   // feature dim
constexpr int OUTF = 128;   // gate MLP out dim
constexpr int G4  = 512;    // 4 gates * 128

typedef __attribute__((ext_vector_type(8))) short short8v;
typedef __attribute__((ext_vector_type(4))) float f32x4;

__device__ __forceinline__ float sigmoid_relu(float z) {
    z = fmaxf(z, 0.0f);
    return 1.0f / (1.0f + __expf(-z));
}
__device__ __forceinline__ float b2f(ushort u) {
    return __uint_as_float(((unsigned int)u) << 16);
}
__device__ __forceinline__ ushort f2b(float f) {  // RNE
    unsigned int x = __float_as_uint(f);
    return (ushort)((x + 0x7fffu + ((x >> 16) & 1u)) >> 16);
}
__device__ __forceinline__ unsigned int pack2(float a, float b) {
    return (unsigned int)f2b(a) | ((unsigned int)f2b(b) << 16);
}

#define GLD16(gptr, lptr) \
    __builtin_amdgcn_global_load_lds((__attribute__((address_space(1))) const void*)(gptr), \
                                     (__attribute__((address_space(3))) void*)(lptr), 16, 0, 0)
// Counted-vmcnt pipeline primitives (T4): keep just-issued loads in flight.
#define ASM_VMCNT(n) asm volatile("s_waitcnt vmcnt(" #n ")" ::: "memory")
#define BARRIER() do { asm volatile("" ::: "memory"); \
                       __builtin_amdgcn_s_barrier();  \
                       asm volatile("" ::: "memory"); } while (0)

// ---------------------------------------------------------------------------
// Fused prep: counter zeroing, f32->bf16 features, gate-weight pack,
// refine-weight transpose.  (Zeroing here removes a 40 us fillBuffer dispatch.)
constexpr int NCNT    = 2 * (NN + NN + PP);        // 20480 ints (cnt + cur)
constexpr int NB_ZERO = NCNT / 256;                // 80
constexpr int NB_F2B  = (NN + PP) * DD / 4 / 256;  // 6144
constexpr int NB_PACK = G4 * DD / 256;             // 2048
constexpr int NB_WT   = 4 * (DD / 64) * (DD / 64); // 1024

__global__ __launch_bounds__(256) void prep_kernel(
        int* __restrict__ cntBlock,
        const float* __restrict__ instF, const float* __restrict__ phraF,
        ushort* __restrict__ instB, ushort* __restrict__ phraB,
        const float* __restrict__ psW, const float* __restrict__ poW,
        const float* __restrict__ opW, const float* __restrict__ spW,
        const float* __restrict__ psB, const float* __restrict__ poB,
        const float* __restrict__ opB, const float* __restrict__ spB,
        ushort* __restrict__ WiT, ushort* __restrict__ WpT,
        float* __restrict__ biascat,
        const float* __restrict__ W0, const float* __restrict__ W1,
        const float* __restrict__ W2, const float* __restrict__ W3,
        ushort* __restrict__ T0, ushort* __restrict__ T1,
        ushort* __restrict__ T2, ushort* __restrict__ T3) {
    __shared__ float tile[64][65];
    int b = blockIdx.x, t = threadIdx.x;
    if (b < NB_ZERO) {
        cntBlock[b * 256 + t] = 0;
        return;
    }
    b -= NB_ZERO;
    if (b < NB_F2B) {
        int i = b * 256 + t;
        constexpr int na4 = NN * DD / 4;
        if (i < na4) {
            float4 v = ((const float4*)instF)[i];
            ushort4 u; u.x = f2b(v.x); u.y = f2b(v.y); u.z = f2b(v.z); u.w = f2b(v.w);
            ((ushort4*)instB)[i] = u;
        } else {
            int j = i - na4;
            float4 v = ((const float4*)phraF)[j];
            ushort4 u; u.x = f2b(v.x); u.y = f2b(v.y); u.z = f2b(v.z); u.w = f2b(v.w);
            ((ushort4*)phraB)[j] = u;
        }
        return;
    }
    b -= NB_F2B;
    if (b < NB_PACK) {
        int idx = b * 256 + t;
        int n = idx >> 10, k = idx & 1023;
        int g = n >> 7, j = n & 127;
        float wi, wp;
        if (g == 0)      { wi = psW[(size_t)(DD + k) * OUTF + j]; wp = psW[(size_t)k * OUTF + j]; }
        else if (g == 1) { wi = poW[(size_t)(DD + k) * OUTF + j]; wp = poW[(size_t)k * OUTF + j]; }
        else if (g == 2) { wi = opW[(size_t)k * OUTF + j];        wp = opW[(size_t)(DD + k) * OUTF + j]; }
        else             { wi = spW[(size_t)k * OUTF + j];        wp = spW[(size_t)(DD + k) * OUTF + j]; }
        WiT[idx] = f2b(wi);
        WpT[idx] = f2b(wp);
        if (idx < G4) {
            int gg = idx >> 7, jj = idx & 127;
            biascat[idx] = (gg == 0) ? psB[jj] : (gg == 1) ? poB[jj]
                         : (gg == 2) ? opB[jj] : spB[jj];
        }
        return;
    }
    b -= NB_PACK;
    int z = b >> 8, rest = b & 255;
    const float* W = (z == 0) ? W0 : (z == 1) ? W1 : (z == 2) ? W2 : W3;
    ushort*      T = (z == 0) ? T0 : (z == 1) ? T1 : (z == 2) ? T2 : T3;
    int k0 = (rest & 15) * 64, n0 = (rest >> 4) * 64;
    int tx = t & 63, ty = t >> 6;
    #pragma unroll
    for (int i = 0; i < 64; i += 4)
        tile[ty + i][tx] = W[(size_t)(k0 + ty + i) * DD + n0 + tx];
    __syncthreads();
    #pragma unroll
    for (int i = 0; i < 64; i += 4)
        T[(size_t)(n0 + ty + i) * DD + k0 + tx] = f2b(tile[tx][ty + i]);
}

// ---------------------------------------------------------------------------
// Pipelined MFMA GEMM building blocks. A-tile 128 rows; B-tile BROWS rows.
// BK=64, XOR-swizzled linear LDS (rule 21).
template<int BROWS>
__device__ __forceinline__ void stage_tiles(const ushort* __restrict__ A,
                                            const ushort* __restrict__ BT,
                                            int bm, int bn, int k0,
                                            ushort* Asl, ushort* Bsl, int t) {
    #pragma unroll
    for (int r = 0; r < 4; r++) {
        int ch = r * 256 + t;
        int row = ch >> 3;
        int sw = ((ch & 7) ^ (row & 7)) << 3;
        GLD16(A + (size_t)(bm + row) * DD + k0 + sw, &Asl[ch * 8]);
    }
    #pragma unroll
    for (int r = 0; r < BROWS / 32; r++) {
        int ch = r * 256 + t;
        int row = ch >> 3;
        int sw = ((ch & 7) ^ (row & 7)) << 3;
        GLD16(BT + (size_t)(bn + row) * DD + k0 + sw, &Bsl[ch * 8]);
    }
}

template<int NACC>
__device__ __forceinline__ void compute_tiles(const ushort* Asl, const ushort* Bsl,
                                              f32x4 (&acc)[4][NACC],
                                              int wr, int wc, int lr, int lk) {
    #pragma unroll
    for (int kk = 0; kk < 2; kk++) {
        int ch16 = kk * 4 + lk;
        short8v a[4], b[NACC];
        #pragma unroll
        for (int m = 0; m < 4; m++) {
            int ra = wr + m * 16 + lr;
            a[m] = *(const short8v*)&Asl[ra * 64 + ((ch16 ^ (ra & 7)) << 3)];
        }
        #pragma unroll
        for (int n = 0; n < NACC; n++) {
            int rb = wc + n * 16 + lr;
            b[n] = *(const short8v*)&Bsl[rb * 64 + ((ch16 ^ (rb & 7)) << 3)];
        }
        #pragma unroll
        for (int m = 0; m < 4; m++)
            #pragma unroll
            for (int n = 0; n < NACC; n++)
                acc[m][n] = __builtin_amdgcn_mfma_f32_16x16x32_bf16(a[m], b[n], acc[m][n], 0, 0, 0);
    }
}

// ---------------------------------------------------------------------------
// Gate tables, 128x64 tile, counted-vmcnt 2-buffer pipeline.
__global__ __launch_bounds__(256) void mfma_tables_kernel(
        const ushort* __restrict__ instB, const ushort* __restrict__ WiT,
        const ushort* __restrict__ phraB, const ushort* __restrict__ WpT,
        const float* __restrict__ biascat,
        ushort* __restrict__ TiB, ushort* __restrict__ TpB) {
    __shared__ ushort Asl[2][128 * 64];
    __shared__ ushort Bsl[2][64 * 64];
    int bx = blockIdx.x;
    const ushort *A, *BT; ushort* C; const float* bias;
    if (bx < NN / 128) { A = instB; BT = WiT; C = TiB; bias = nullptr; }
    else { bx -= NN / 128; A = phraB; BT = WpT; C = TpB; bias = biascat; }
    int bm = bx * 128, bn = blockIdx.y * 64;
    int t = threadIdx.x;
    const int lane = t & 63, w = t >> 6;
    const int wr = (w >> 1) * 64, wc = (w & 1) * 32;
    const int lr = lane & 15, lk = lane >> 4;
    f32x4 acc[4][2] = {};

    int cur = 0;
    stage_tiles<64>(A, BT, bm, bn, 0, Asl[0], Bsl[0], t);
    for (int k0 = 0; k0 < DD; k0 += 64) {
        int nxt = cur ^ 1;
        if (k0 + 64 < DD) {
            stage_tiles<64>(A, BT, bm, bn, k0 + 64, Asl[nxt], Bsl[nxt], t);
            ASM_VMCNT(6);
        } else {
            ASM_VMCNT(0);
        }
        BARRIER();
        compute_tiles<2>(Asl[cur], Bsl[cur], acc, wr, wc, lr, lk);
        BARRIER();
        cur = nxt;
    }
    #pragma unroll
    for (int m = 0; m < 4; m++) {
        int row = bm + wr + m * 16 + lk * 4;
        #pragma unroll
        for (int n = 0; n < 2; n++) {
            int col = bn + wc + n * 16 + lr;
            float bv = bias ? bias[col] : 0.f;
            #pragma unroll
            for (int r = 0; r < 4; r++)
                C[(size_t)(row + r) * G4 + col] = f2b(acc[m][n][r] + bv);
        }
    }
}

// ---------------------------------------------------------------------------
// Fused refine: out = msg + relu(msg@W1+b1) + relu(feat@W2+b2).
// 128x64 tile (768 blocks), continuous counted-vmcnt pipeline.
__global__ __launch_bounds__(256) void mfma_refine_kernel(
        const ushort* __restrict__ imsgB, const ushort* __restrict__ instB,
        const ushort* __restrict__ iw1T, const ushort* __restrict__ iw2T,
        const float* __restrict__ ib1, const float* __restrict__ ib2,
        float* __restrict__ iout,
        const ushort* __restrict__ pmsgB, const ushort* __restrict__ phraB,
        const ushort* __restrict__ pw1T, const ushort* __restrict__ pw2T,
        const float* __restrict__ pb1, const float* __restrict__ pb2,
        float* __restrict__ pout) {
    __shared__ ushort Asl[2][128 * 64];
    __shared__ ushort Bsl[2][64 * 64];
    int bx = blockIdx.x;
    const ushort *Am, *Af, *W1, *W2; const float *b1, *b2; float* out;
    if (bx < NN / 128) {
        Am = imsgB; Af = instB; W1 = iw1T; W2 = iw2T; b1 = ib1; b2 = ib2; out = iout;
    } else {
        bx -= NN / 128;
        Am = pmsgB; Af = phraB; W1 = pw1T; W2 = pw2T; b1 = pb1; b2 = pb2; out = pout;
    }
    int bm = bx * 128, bn = blockIdx.y * 64;
    int t = threadIdx.x;
    const int lane = t & 63, w = t >> 6;
    const int wr = (w >> 1) * 64, wc = (w & 1) * 32;
    const int lr = lane & 15, lk = lane >> 4;
    f32x4 acc1[4][2] = {};
    f32x4 acc2[4][2] = {};

    int cur = 0;
    stage_tiles<64>(Am, W1, bm, bn, 0, Asl[0], Bsl[0], t);
    auto run = [&](const ushort* A, const ushort* B, f32x4 (&acc)[4][2],
                   const ushort* An, const ushort* Bn) {
        for (int k0 = 0; k0 < DD; k0 += 64) {
            int nxt = cur ^ 1;
            if (k0 + 64 < DD) {
                stage_tiles<64>(A, B, bm, bn, k0 + 64, Asl[nxt], Bsl[nxt], t);
                ASM_VMCNT(6);
            } else if (An) {
                stage_tiles<64>(An, Bn, bm, bn, 0, Asl[nxt], Bsl[nxt], t);
                ASM_VMCNT(6);
            } else {
                ASM_VMCNT(0);
            }
            BARRIER();
            compute_tiles<2>(Asl[cur], Bsl[cur], acc, wr, wc, lr, lk);
            BARRIER();
            cur = nxt;
        }
    };
    run(Am, W1, acc1, Af, W2);
    run(Af, W2, acc2, nullptr, nullptr);

    #pragma unroll
    for (int m = 0; m < 4; m++) {
        int row = bm + wr + m * 16 + lk * 4;
        #pragma unroll
        for (int n = 0; n < 2; n++) {
            int col = bn + wc + n * 16 + lr;
            float vb1 = b1[col], vb2 = b2[col];
            #pragma unroll
            for (int r = 0; r < 4; r++) {
                float v = b2f(Am[(size_t)(row + r) * DD + col])
                        + fmaxf(acc1[m][n][r] + vb1, 0.f)
                        + fmaxf(acc2[m][n][r] + vb2, 0.f);
                out[(size_t)(row + r) * DD + col] = v;
            }
        }
    }
}

// ---------------------------------------------------------------------------
// Counting sort: histogram + scan (scatter is folded into gate_kernel).
__global__ void hist_kernel(const int* __restrict__ s_idx, const int* __restrict__ o_idx,
                            const int* __restrict__ c_idx,
                            int* cntS, int* cntO, int* cntC) {
    int e = blockIdx.x * blockDim.x + threadIdx.x;
    if (e >= EE) return;
    atomicAdd(&cntS[s_idx[e]], 1);
    atomicAdd(&cntO[o_idx[e]], 1);
    atomicAdd(&cntC[c_idx[e]], 1);
}

__global__ __launch_bounds__(1024) void scan3_kernel(
        const int* __restrict__ cntS, const int* __restrict__ cntO,
        const int* __restrict__ cntC,
        int* __restrict__ startS, int* __restrict__ startO, int* __restrict__ startC) {
    const int* cnt; int* start; int n;
    if (blockIdx.x == 0)      { cnt = cntS; start = startS; n = NN; }
    else if (blockIdx.x == 1) { cnt = cntO; start = startO; n = NN; }
    else                      { cnt = cntC; start = startC; n = PP; }
    __shared__ int sh[1024];
    int t = threadIdx.x;
    int per = n >> 10;
    int base = t * per;
    int s = 0;
    for (int i = 0; i < per; i++) s += cnt[base + i];
    sh[t] = s;
    __syncthreads();
    for (int off = 1; off < 1024; off <<= 1) {
        int v = (t >= off) ? sh[t - off] : 0;
        __syncthreads();
        sh[t] += v;
        __syncthreads();
    }
    int ex = (t == 0) ? 0 : sh[t - 1];
    for (int i = 0; i < per; i++) { start[base + i] = ex; ex += cnt[base + i]; }
    if (t == 1023) start[n] = ex;
}

// ---------------------------------------------------------------------------
// Per-edge gates; computes CSR slot (scatter fused) and writes packed entries.
__global__ __launch_bounds__(256) void gate_kernel(
        const int* __restrict__ s_idx, const int* __restrict__ o_idx,
        const int* __restrict__ c_idx,
        const int* __restrict__ startS, const int* __restrict__ startO,
        const int* __restrict__ startC,
        int* __restrict__ curS, int* __restrict__ curO, int* __restrict__ curC,
        const ushort* __restrict__ Ti, const ushort* __restrict__ Tp,
        int2* __restrict__ pkS, int2* __restrict__ pkO, int4* __restrict__ pkC) {
    int gid = blockIdx.x * 256 + threadIdx.x;
    int e = gid >> 6, lane = gid & 63;
    if (e >= EE) return;
    int s = s_idx[e], o = o_idx[e], c = c_idx[e];
    const unsigned int* tpc = (const unsigned int*)(Tp + (size_t)c * G4);
    const unsigned int* tis = (const unsigned int*)(Ti + (size_t)s * G4);
    const unsigned int* tio = (const unsigned int*)(Ti + (size_t)o * G4);
    auto pairSig = [](unsigned int a, unsigned int b) {
        float lo = __uint_as_float(a << 16) + __uint_as_float(b << 16);
        float hi = __uint_as_float(a & 0xffff0000u) + __uint_as_float(b & 0xffff0000u);
        return sigmoid_relu(lo) + sigmoid_relu(hi);
    };
    float s0 = pairSig(tpc[lane],       tis[lane]);
    float s1 = pairSig(tpc[64 + lane],  tio[64 + lane]);
    float s2 = pairSig(tpc[128 + lane], tio[128 + lane]);
    float s3 = pairSig(tpc[192 + lane], tis[192 + lane]);
    #pragma unroll
    for (int off = 32; off; off >>= 1) {
        s0 += __shfl_xor(s0, off);
        s1 += __shfl_xor(s1, off);
        s2 += __shfl_xor(s2, off);
        s3 += __shfl_xor(s3, off);
    }
    if (lane == 0) {
        const float inv = 1.0f / 128.0f;
        int ps = startS[s] + atomicAdd(&curS[s], 1);
        int po = startO[o] + atomicAdd(&curO[o], 1);
        int pc = startC[c] + atomicAdd(&curC[c], 1);
        pkS[ps] = make_int2(c, __float_as_int(s0 * inv));
        pkO[po] = make_int2(c, __float_as_int(s1 * inv));
        pkC[pc] = make_int4(o, s, __float_as_int(s2 * inv), __float_as_int(s3 * inv));
    }
}

// ---------------------------------------------------------------------------
__device__ __forceinline__ void accum8(float* acc, uint4 v, float g) {
    acc[0] += g * __uint_as_float(v.x << 16);
    acc[1] += g * __uint_as_float(v.x & 0xffff0000u);
    acc[2] += g * __uint_as_float(v.y << 16);
    acc[3] += g * __uint_as_float(v.y & 0xffff0000u);
    acc[4] += g * __uint_as_float(v.z << 16);
    acc[5] += g * __uint_as_float(v.z & 0xffff0000u);
    acc[6] += g * __uint_as_float(v.w << 16);
    acc[7] += g * __uint_as_float(v.w & 0xffff0000u);
}

// Merged segment means: blocks [0, NN/2) = inst side, rest = phra side.
__global__ __launch_bounds__(256) void seg_kernel(
        const ushort* __restrict__ phraB, const ushort* __restrict__ instB,
        const int2* __restrict__ pkS, const int* __restrict__ startS,
        const int2* __restrict__ pkO, const int* __restrict__ startO,
        const int4* __restrict__ pkC, const int* __restrict__ startC,
        ushort* __restrict__ imsgB, ushort* __restrict__ pmsgB) {
    __shared__ float lds[4][64 * 17];
    int w = threadIdx.x >> 6, lane = threadIdx.x & 63;
    float acc[16];
    #pragma unroll
    for (int j = 0; j < 16; j++) acc[j] = 0.f;
    int bx = blockIdx.x;
    bool instSide = bx < NN / 2;
    int segB, segE;           // for scale
    ushort* msgB;
    int base2;
    if (instSide) {
        int node = bx * 2 + (w >> 1);
        const int2* pk_list = (w & 1) ? pkO : pkS;
        const int*  start   = (w & 1) ? startO : startS;
        int b = start[node], e = start[node + 1];
        if (b < e) {
            int2 pk = pk_list[b];
            const uint4* r = (const uint4*)(phraB + (size_t)pk.x * DD) + lane;
            uint4 c0 = r[0], c1 = r[64];
            for (int i = b + 1; i < e; i++) {
                int2 pkn = pk_list[i];
                const uint4* rn = (const uint4*)(phraB + (size_t)pkn.x * DD) + lane;
                uint4 n0 = rn[0], n1 = rn[64];
                float g = __int_as_float(pk.y);
                accum8(acc, c0, g); accum8(acc + 8, c1, g);
                pk = pkn; c0 = n0; c1 = n1;
            }
            float g = __int_as_float(pk.y);
            accum8(acc, c0, g); accum8(acc + 8, c1, g);
        }
        segB = b; segE = e; msgB = imsgB; base2 = bx * 2;
    } else {
        int pbx = bx - NN / 2;
        int p = pbx * 2 + (w >> 1);
        int half = w & 1;
        int cb = startC[p], ce = startC[p + 1];
        int i0 = cb + half;
        if (i0 < ce) {
            int4 pk = pkC[i0];
            const uint4* ro = (const uint4*)(instB + (size_t)pk.x * DD) + lane;
            const uint4* rs = (const uint4*)(instB + (size_t)pk.y * DD) + lane;
            uint4 o0 = ro[0], o1 = ro[64], s0 = rs[0], s1 = rs[64];
            for (int i = i0 + 2; i < ce; i += 2) {
                int4 pkn = pkC[i];
                const uint4* rno = (const uint4*)(instB + (size_t)pkn.x * DD) + lane;
                const uint4* rns = (const uint4*)(instB + (size_t)pkn.y * DD) + lane;
                uint4 no0 = rno[0], no1 = rno[64], ns0 = rns[0], ns1 = rns[64];
                float go = __int_as_float(pk.z), gs = __int_as_float(pk.w);
                accum8(acc, o0, go); accum8(acc + 8, o1, go);
                accum8(acc, s0, gs); accum8(acc + 8, s1, gs);
                pk = pkn; o0 = no0; o1 = no1; s0 = ns0; s1 = ns1;
            }
            float go = __int_as_float(pk.z), gs = __int_as_float(pk.w);
            accum8(acc, o0, go); accum8(acc + 8, o1, go);
            accum8(acc, s0, gs); accum8(acc + 8, s1, gs);
        }
        segB = cb; segE = ce; msgB = pmsgB; base2 = pbx * 2;
    }
    float scale = 0.5f / (float)max(segE - segB, 1);
    #pragma unroll
    for (int j = 0; j < 16; j++) lds[w][lane * 17 + j] = acc[j] * scale;
    __syncthreads();
    int u = threadIdx.x & 127;
    int outrow = base2 + (threadIdx.x >> 7);
    int w0 = (threadIdx.x >> 7) << 1;
    int off = (u & 63) * 17 + (u >> 6) * 8;
    float4 a0 = *(const float4*)&lds[w0][off];
    float4 a1 = *(const float4*)&lds[w0][off + 4];
    float4 b0 = *(const float4*)&lds[w0 + 1][off];
    float4 b1 = *(const float4*)&lds[w0 + 1][off + 4];
    uint4 o;
    o.x = pack2(a0.x + b0.x, a0.y + b0.y);
    o.y = pack2(a0.z + b0.z, a0.w + b0.w);
    o.z = pack2(a1.x + b1.x, a1.y + b1.y);
    o.w = pack2(a1.z + b1.z, a1.w + b1.w);
    *(uint4*)&msgB[(size_t)outrow * DD + u * 8] = o;
}

// ---------------------------------------------------------------------------
extern "C" void kernel_launch(void* const* d_in, const int* in_sizes, int n_in,
                              void* d_out, int out_size, void* d_ws, size_t ws_size,
                              hipStream_t stream) {
    (void)in_sizes; (void)n_in; (void)out_size; (void)ws_size;
    const float* inst_feat = (const float*)d_in[0];
    const float* phra_feat = (const float*)d_in[1];
    const int*   conn      = (const int*)d_in[2];
    const int*   clu       = (const int*)d_in[3];
    const float* psW = (const float*)d_in[4];  const float* psB = (const float*)d_in[5];
    const float* poW = (const float*)d_in[6];  const float* poB = (const float*)d_in[7];
    const float* opW = (const float*)d_in[8];  const float* opB = (const float*)d_in[9];
    const float* spW = (const float*)d_in[10]; const float* spB = (const float*)d_in[11];
    const float* iw1W = (const float*)d_in[12]; const float* iw1B = (const float*)d_in[13];
    const float* iw2W = (const float*)d_in[14]; const float* iw2B = (const float*)d_in[15];
    const float* pw1W = (const float*)d_in[16]; const float* pw1B = (const float*)d_in[17];
    const float* pw2W = (const float*)d_in[18]; const float* pw2B = (const float*)d_in[19];
    const int* s_idx = conn;
    const int* o_idx = conn + EE;

    char* ws = (char*)d_ws;
    size_t off = 0;
    auto alloc = [&](size_t bytes) {
        char* p = ws + off;
        off += (bytes + 255) & ~(size_t)255;
        return p;
    };
    ushort* instB = (ushort*)alloc((size_t)NN * DD * 2);
    ushort* phraB = (ushort*)alloc((size_t)PP * DD * 2);
    ushort* WiT   = (ushort*)alloc((size_t)G4 * DD * 2);
    ushort* WpT   = (ushort*)alloc((size_t)G4 * DD * 2);
    ushort* iw1T  = (ushort*)alloc((size_t)DD * DD * 2);
    ushort* iw2T  = (ushort*)alloc((size_t)DD * DD * 2);
    ushort* pw1T  = (ushort*)alloc((size_t)DD * DD * 2);
    ushort* pw2T  = (ushort*)alloc((size_t)DD * DD * 2);
    float* biascat = (float*)alloc(G4 * 4);
    ushort* TiB   = (ushort*)alloc((size_t)NN * G4 * 2);
    ushort* TpB   = (ushort*)alloc((size_t)PP * G4 * 2);
    int* cntBlock = (int*)alloc((size_t)NCNT * 4);
    int* cntS = cntBlock;      int* cntO = cntS + NN;  int* cntC = cntO + NN;
    int* curS = cntC + PP;     int* curO = curS + NN;  int* curC = curO + NN;
    int* startS = (int*)alloc((NN + 1) * 4);
    int* startO = (int*)alloc((NN + 1) * 4);
    int* startC = (int*)alloc((PP + 1) * 4);
    int2* pkS   = (int2*)alloc((size_t)EE * 8);
    int2* pkO   = (int2*)alloc((size_t)EE * 8);
    int4* pkC   = (int4*)alloc((size_t)EE * 16);
    ushort* imsgB = (ushort*)alloc((size_t)NN * DD * 2);
    ushort* pmsgB = (ushort*)alloc((size_t)PP * DD * 2);

    float* inst_out = (float*)d_out;
    float* phra_out = inst_out + (size_t)NN * DD;

    // Fused prep: counter zeroing + bf16 casts + weight pack/transpose
    prep_kernel<<<NB_ZERO + NB_F2B + NB_PACK + NB_WT, 256, 0, stream>>>(
        cntBlock, inst_feat, phra_feat, instB, phraB,
        psW, poW, opW, spW, psB, poB, opB, spB, WiT, WpT, biascat,
        iw1W, iw2W, pw1W, pw2W, iw1T, iw2T, pw1T, pw2T);

    // CSR build (scatter folded into gate_kernel)
    hist_kernel<<<EE / 256, 256, 0, stream>>>(s_idx, o_idx, clu, cntS, cntO, cntC);
    scan3_kernel<<<3, 1024, 0, stream>>>(cntS, cntO, cntC, startS, startO, startC);

    // Gate tables (bf16 MFMA, bias folded into Tp)
    mfma_tables_kernel<<<dim3((NN + PP) / 128, G4 / 64), 256, 0, stream>>>(
        instB, WiT, phraB, WpT, biascat, TiB, TpB);

    // Gates -> packed CSR entries (scatter fused)
    gate_kernel<<<(EE * 64) / 256, 256, 0, stream>>>(
        s_idx, o_idx, clu, startS, startO, startC, curS, curO, curC,
        TiB, TpB, pkS, pkO, pkC);

    // Segment means (merged inst + phra)
    seg_kernel<<<NN / 2 + PP / 2, 256, 0, stream>>>(
        phraB, instB, pkS, startS, pkO, startO, pkC, startC, imsgB, pmsgB);

    // Fused refine (128x64 tiles, 768 blocks, counted-vmcnt pipeline)
    mfma_refine_kernel<<<dim3((NN + PP) / 128, DD / 64), 256, 0, stream>>>(
        imsgB, instB, iw1T, iw2T, iw1B, iw2B, inst_out,
        pmsgB, phraB, pw1T, pw2T, pw1B, pw2B, phra_out);
}